// Round 13
// baseline (977.595 us; speedup 1.0000x reference)
//
#include <hip/hip_runtime.h>

typedef unsigned short u16;
typedef unsigned int u32;
typedef __bf16 bf16x8 __attribute__((ext_vector_type(8)));
typedef float f32x4 __attribute__((ext_vector_type(4)));

#define ND 512
#define DWR 300
#define DWP 320
#define NCLS 13

__device__ __forceinline__ float bf2f(u16 u) { return __uint_as_float(((u32)u) << 16); }
__device__ __forceinline__ u16 f2bf(float f) {
    u32 u = __float_as_uint(f);
    u32 r = (u + 0x7FFFu + ((u >> 16) & 1u)) >> 16;
    return (u16)r;
}
__device__ __forceinline__ void ub8(float4 r, float* v) {
    union { float4 f; u16 u[8]; } U; U.f = r;
#pragma unroll
    for (int k = 0; k < 8; ++k) v[k] = bf2f(U.u[k]);
}
__device__ __forceinline__ void ld8f(const u16* p, float* v) { ub8(*(const float4*)p, v); }
// bijective 1-D XCD swizzle (m204): consecutive results share an XCD
__device__ __forceinline__ int xcd_swz(int b, int gx) {
    const int q = gx >> 3, r = gx & 7;
    const int x = b & 7, o = b >> 3;
    return (x < r ? x * (q + 1) : r * (q + 1) + (x - r) * q) + o;
}

struct GSeg { const u16* base; const int* idx; int stride; int width; };
struct GSegs { GSeg s[5]; };
struct TSeg { int src_begin; int wreal; int wpad; };
struct TSegs { TSeg t[5]; };

// ---------------- node-domain GEMM: C = [relu](A @ BT^T + bias), bf16 out ----------------
template<int RELU>
__global__ __launch_bounds__(256) void gemm_k(
    int M, int Nout, GSegs segs,
    const u16* __restrict__ BT, int ldb,
    const float* __restrict__ bias, int bias_n,
    u16* __restrict__ outb, int ldo)
{
    __shared__ __align__(16) u16 As[128 * 40];
    __shared__ __align__(16) u16 Bs[128 * 40];
    const int tid = threadIdx.x;

    const int gx = gridDim.x, gy = gridDim.y;
    const int g0 = blockIdx.x + gx * blockIdx.y;
    int xt, yt;
    {
        const int fullg = gx >> 3;
        const int gsz = 8 * gy;
        if (g0 < fullg * gsz) {
            const int grp = g0 / gsz, w = g0 % gsz;
            xt = grp * 8 + (w & 7); yt = w >> 3;
        } else {
            const int remx = gx - fullg * 8;
            const int t = g0 - fullg * gsz;
            xt = fullg * 8 + t % remx; yt = t / remx;
        }
    }
    const int m0 = xt * 128, n0 = yt * 128;

    const int row = tid >> 1, half = tid & 1;
    int mrow = m0 + row; if (mrow >= M) mrow = M - 1;
    const int lane = tid & 63, wid = tid >> 6;
    const int wr = (wid >> 1) * 64, wc = (wid & 1) * 64;
    const int lr = lane & 15, lg = lane >> 4;

    f32x4 acc[4][4];
    for (int fm = 0; fm < 4; fm++)
        for (int fn = 0; fn < 4; fn++)
            acc[fm][fn] = f32x4{0.f, 0.f, 0.f, 0.f};

    const u16* brow = BT + (size_t)(n0 + row) * ldb + half * 16;

    auto do_step = [&](const u16* ga_, const u16* gb_) {
        float4 a0 = *(const float4*)ga_;
        float4 a1 = *(const float4*)(ga_ + 8);
        float4 b0 = *(const float4*)gb_;
        float4 b1 = *(const float4*)(gb_ + 8);
        __syncthreads();
        *(float4*)&As[row * 40 + half * 16]     = a0;
        *(float4*)&As[row * 40 + half * 16 + 8] = a1;
        *(float4*)&Bs[row * 40 + half * 16]     = b0;
        *(float4*)&Bs[row * 40 + half * 16 + 8] = b1;
        __syncthreads();
        bf16x8 af[4], bfv[4];
#pragma unroll
        for (int f = 0; f < 4; f++) {
            af[f]  = *(const bf16x8*)&As[(wr + f * 16 + lr) * 40 + lg * 8];
            bfv[f] = *(const bf16x8*)&Bs[(wc + f * 16 + lr) * 40 + lg * 8];
        }
#pragma unroll
        for (int fm = 0; fm < 4; fm++)
#pragma unroll
            for (int fn = 0; fn < 4; fn++)
                acc[fm][fn] = __builtin_amdgcn_mfma_f32_16x16x32_bf16(af[fm], bfv[fn], acc[fm][fn], 0, 0, 0);
    };

    int k0 = 0;
#pragma unroll
    for (int sI = 0; sI < 5; sI++) {
        const GSeg S = segs.s[sI];
        if (S.width > 0) {
            const int ridx = S.idx ? S.idx[mrow] : mrow;
            const u16* abase = S.base + (size_t)ridx * S.stride + half * 16;
            for (int kk = 0; kk < S.width; kk += 32) {
                do_step(abase + kk, brow + k0 + kk);
            }
            k0 += S.width;
        }
    }

#pragma unroll
    for (int fm = 0; fm < 4; fm++) {
#pragma unroll
        for (int i = 0; i < 4; i++) {
            const int grow = m0 + wr + fm * 16 + lg * 4 + i;
            const bool rok = grow < M;
#pragma unroll
            for (int fn = 0; fn < 4; fn++) {
                const int col = n0 + wc + fn * 16 + lr;
                float v = acc[fm][fn][i];
                v += (col < bias_n) ? bias[col] : 0.f;
                if (RELU) v = fmaxf(v, 0.f);
                if (rok && col < Nout) outb[(size_t)grow * ldo + col] = f2bf(v);
            }
        }
    }
}

// ---------------- pass 1: attention logits as MFMA edge-tile, sfw via MFMA ----------------
__global__ __launch_bounds__(256) void pass1_k(
    const u16* __restrict__ Q, const u16* __restrict__ Lq,
    const float* __restrict__ s_f, const float* __restrict__ wmid,
    const int* __restrict__ psrc, const int* __restrict__ pdst, const int* __restrict__ perm,
    const float* __restrict__ W_a, const float* __restrict__ W_al,
    const float* __restrict__ b_e, const float* __restrict__ b_el,
    const float* __restrict__ b_a, const float* __restrict__ b_al,
    float* __restrict__ aA, float* __restrict__ aL, int E)
{
    __shared__ __align__(16) u16 sfs_bf[128 * 40];
    __shared__ __align__(16) u16 wmidT[512 * 16];
    __shared__ __align__(16) u16 As_v[128 * 40];
    __shared__ __align__(16) u16 As_l[128 * 40];
    __shared__ __align__(16) float sfw[128 * 36];
    __shared__ float bes[512], bels[512];
    __shared__ __align__(16) u16 was[512], wals[512];

    const int tid = threadIdx.x;
    const int e0 = xcd_swz(blockIdx.x, gridDim.x) * 128;

    for (int i = tid; i < 512 * 16; i += 256) {
        const int col = i >> 4, k = i & 15;
        wmidT[i] = f2bf(wmid[k * 512 + col]);
    }
    for (int i = tid; i < 512; i += 256) {
        bes[i] = b_e[i]; bels[i] = b_el[i];
        was[i] = f2bf(W_a[i]); wals[i] = f2bf(W_al[i]);
    }

    const int row = tid >> 1, half = tid & 1;
    const int er = e0 + row;
    const int erc = (er < E) ? er : E - 1;
    {
        const int pe = perm[erc];
        const float4* sp = (const float4*)(s_f + (size_t)pe * 16 + half * 8);
        float4 a = sp[0], b = sp[1];
        union { float4 f; u16 u[8]; } S;
        S.u[0]=f2bf(a.x); S.u[1]=f2bf(a.y); S.u[2]=f2bf(a.z); S.u[3]=f2bf(a.w);
        S.u[4]=f2bf(b.x); S.u[5]=f2bf(b.y); S.u[6]=f2bf(b.z); S.u[7]=f2bf(b.w);
        *(float4*)&sfs_bf[row * 40 + half * 8] = S.f;
        S.f = float4{0.f, 0.f, 0.f, 0.f};
        *(float4*)&sfs_bf[row * 40 + 16 + half * 8] = S.f;
    }

    const int ps = psrc[erc], pd = pdst[erc];
    const u16* q1b = Q + (size_t)ps * 1024;
    const u16* q2b = Q + (size_t)pd * 1024 + 512;
    const u16* l1b = Lq + (size_t)ps * 1024;
    const u16* l2b = Lq + (size_t)pd * 1024 + 512;

    const int lane = tid & 63, wid = tid >> 6;
    const int lr = lane & 15, lg = lane >> 4;
    f32x4 accv[2], accl[2];
    accv[0] = accv[1] = accl[0] = accl[1] = f32x4{0.f, 0.f, 0.f, 0.f};
    union { bf16x8 v; float4 f; } BZ; BZ.f = float4{0.f, 0.f, 0.f, 0.f};

    __syncthreads();

    for (int ch = 0; ch < 16; ++ch) {
        const int k0 = ch * 32 + half * 16;
#pragma unroll
        for (int rt = 0; rt < 2; ++rt) {
            bf16x8 af = *(const bf16x8*)&sfs_bf[((wid * 2 + rt) * 16 + lr) * 40 + lg * 8];
#pragma unroll
            for (int ct = 0; ct < 2; ++ct) {
                const int f = ch * 32 + ct * 16 + lr;
                bf16x8 bf_ = *(const bf16x8*)&wmidT[f * 16 + (lg & 1) * 8];
                f32x4 c = __builtin_amdgcn_mfma_f32_16x16x32_bf16(af, bf_, f32x4{0.f,0.f,0.f,0.f}, 0, 0, 0);
#pragma unroll
                for (int i = 0; i < 4; ++i)
                    sfw[((wid * 2 + rt) * 16 + lg * 4 + i) * 36 + ct * 16 + lr] = c[i];
            }
        }
        __syncthreads();

        float4 rq1a = *(const float4*)(q1b + k0);
        float4 rq1b = *(const float4*)(q1b + k0 + 8);
        float4 rq2a = *(const float4*)(q2b + k0);
        float4 rq2b = *(const float4*)(q2b + k0 + 8);
        float4 rl1a = *(const float4*)(l1b + k0);
        float4 rl1b = *(const float4*)(l1b + k0 + 8);
        float4 rl2a = *(const float4*)(l2b + k0);
        float4 rl2b = *(const float4*)(l2b + k0 + 8);
        float sw[16];
        *(float4*)&sw[0]  = *(const float4*)&sfw[row * 36 + half * 16 + 0];
        *(float4*)&sw[4]  = *(const float4*)&sfw[row * 36 + half * 16 + 4];
        *(float4*)&sw[8]  = *(const float4*)&sfw[row * 36 + half * 16 + 8];
        *(float4*)&sw[12] = *(const float4*)&sfw[row * 36 + half * 16 + 12];

        float uv[16], ul[16], t1[8], t2[8];
        ub8(rq1a, t1); ub8(rq2a, t2);
#pragma unroll
        for (int k = 0; k < 8; ++k) uv[k] = t1[k] + t2[k] + bes[k0 + k] + sw[k];
        ub8(rq1b, t1); ub8(rq2b, t2);
#pragma unroll
        for (int k = 0; k < 8; ++k) uv[8 + k] = t1[k] + t2[k] + bes[k0 + 8 + k] + sw[8 + k];
        ub8(rl1a, t1); ub8(rl2a, t2);
#pragma unroll
        for (int k = 0; k < 8; ++k) ul[k] = t1[k] + t2[k] + bels[k0 + k];
        ub8(rl1b, t1); ub8(rl2b, t2);
#pragma unroll
        for (int k = 0; k < 8; ++k) ul[8 + k] = t1[k] + t2[k] + bels[k0 + 8 + k];

        union { float4 f; u16 u[8]; } Va, Vb, La, Lb;
#pragma unroll
        for (int k = 0; k < 8; ++k) {
            Va.u[k] = f2bf(fmaxf(uv[k], 0.f));
            Vb.u[k] = f2bf(fmaxf(uv[8 + k], 0.f));
            La.u[k] = f2bf(fmaxf(ul[k], 0.f));
            Lb.u[k] = f2bf(fmaxf(ul[8 + k], 0.f));
        }
        *(float4*)&As_v[row * 40 + half * 16]     = Va.f;
        *(float4*)&As_v[row * 40 + half * 16 + 8] = Vb.f;
        *(float4*)&As_l[row * 40 + half * 16]     = La.f;
        *(float4*)&As_l[row * 40 + half * 16 + 8] = Lb.f;
        __syncthreads();

        bf16x8 bv = BZ.v, bl = BZ.v;
        if (lr == 0) {
            bv = *(const bf16x8*)&was[ch * 32 + lg * 8];
            bl = *(const bf16x8*)&wals[ch * 32 + lg * 8];
        }
#pragma unroll
        for (int m = 0; m < 2; ++m) {
            bf16x8 afv = *(const bf16x8*)&As_v[(wid * 32 + m * 16 + lr) * 40 + lg * 8];
            bf16x8 afl = *(const bf16x8*)&As_l[(wid * 32 + m * 16 + lr) * 40 + lg * 8];
            accv[m] = __builtin_amdgcn_mfma_f32_16x16x32_bf16(afv, bv, accv[m], 0, 0, 0);
            accl[m] = __builtin_amdgcn_mfma_f32_16x16x32_bf16(afl, bl, accl[m], 0, 0, 0);
        }
    }

    if (lr == 0) {
        const float ba = b_a[0], bal = b_al[0];
#pragma unroll
        for (int m = 0; m < 2; ++m) {
#pragma unroll
            for (int i = 0; i < 4; ++i) {
                const int e = e0 + wid * 32 + m * 16 + lg * 4 + i;
                if (e < E) {
                    float x = accv[m][i] + ba;
                    aA[e] = x > 0.f ? x : 0.2f * x;
                    float y = accl[m][i] + bal;
                    aL[e] = y > 0.f ? y : 0.2f * y;
                }
            }
        }
    }
}

// ---------------- softmax: wave-per-node over sorted edges, no atomics ----------------
__global__ __launch_bounds__(256) void softmax_k(
    float* __restrict__ a, float* __restrict__ al,
    const int* __restrict__ offs, int N, int E)
{
    const int node = blockIdx.x * 4 + (threadIdx.x >> 6);
    if (node >= N) return;
    const int lane = threadIdx.x & 63;
    const int e0 = offs[node];
    const int e1 = (node + 1 < N) ? offs[node + 1] : E;
    if (e0 >= e1) return;
    float m = -3.4e38f, ml = -3.4e38f;
    for (int e = e0 + lane; e < e1; e += 64) { m = fmaxf(m, a[e]); ml = fmaxf(ml, al[e]); }
#pragma unroll
    for (int off = 32; off >= 1; off >>= 1) {
        m  = fmaxf(m,  __shfl_xor(m,  off, 64));
        ml = fmaxf(ml, __shfl_xor(ml, off, 64));
    }
    float s = 0.f, sl = 0.f;
    for (int e = e0 + lane; e < e1; e += 64) {
        float v = expf(a[e] - m);   a[e] = v;  s += v;
        float w = expf(al[e] - ml); al[e] = w; sl += w;
    }
#pragma unroll
    for (int off = 32; off >= 1; off >>= 1) {
        s  += __shfl_xor(s,  off, 64);
        sl += __shfl_xor(sl, off, 64);
    }
    const float rs = 1.f / (s + 1e-9f), rsl = 1.f / (sl + 1e-9f);
    for (int e = e0 + lane; e < e1; e += 64) { a[e] *= rs; al[e] *= rsl; }
}

// ---------------- pass z: z aggregation as MFMA edge-tile + segment reduce ----------------
// Per chunk: (1) sfw via MFMA, (2) build alpha*relu(q1+q2+b+sw) in f32 (overwrite
// own sfw slots), (3) dst-run segment reduce per column stripe, atomicAdd per run.
__global__ __launch_bounds__(256) void passzt_k(
    const u16* __restrict__ Q, const float* __restrict__ s_f, const float* __restrict__ wmid,
    const int* __restrict__ psrc, const int* __restrict__ pdst, const int* __restrict__ perm,
    const float* __restrict__ alpha, const float* __restrict__ b_e,
    float* __restrict__ z, int E)
{
    __shared__ __align__(16) u16 sfs_bf[128 * 40];   // 10240 B
    __shared__ __align__(16) u16 wmidT[512 * 16];    // 16384 B
    __shared__ __align__(16) float sfw[128 * 36];    // 18432 B
    __shared__ float bes[512];                       // 2048 B
    __shared__ int pd[128];                          // 512 B
    __shared__ float alf[128];                       // 512 B

    const int tid = threadIdx.x;
    const int e0 = xcd_swz(blockIdx.x, gridDim.x) * 128;

    for (int i = tid; i < 512 * 16; i += 256) {
        const int col = i >> 4, k = i & 15;
        wmidT[i] = f2bf(wmid[k * 512 + col]);
    }
    for (int i = tid; i < 512; i += 256) bes[i] = b_e[i];

    const int row = tid >> 1, half = tid & 1;
    const int er = e0 + row;
    const int erc = (er < E) ? er : E - 1;
    {
        const int pe = perm[erc];
        const float4* sp = (const float4*)(s_f + (size_t)pe * 16 + half * 8);
        float4 a = sp[0], b = sp[1];
        union { float4 f; u16 u[8]; } S;
        S.u[0]=f2bf(a.x); S.u[1]=f2bf(a.y); S.u[2]=f2bf(a.z); S.u[3]=f2bf(a.w);
        S.u[4]=f2bf(b.x); S.u[5]=f2bf(b.y); S.u[6]=f2bf(b.z); S.u[7]=f2bf(b.w);
        *(float4*)&sfs_bf[row * 40 + half * 8] = S.f;
        S.f = float4{0.f, 0.f, 0.f, 0.f};
        *(float4*)&sfs_bf[row * 40 + 16 + half * 8] = S.f;
    }
    if (half == 0) {
        pd[row] = pdst[erc];
        alf[row] = (er < E) ? alpha[er] : 0.f;   // guard rows contribute 0
    }

    const int ps = psrc[erc], pdn = pdst[erc];
    const u16* q1b = Q + (size_t)ps * 1024;
    const u16* q2b = Q + (size_t)pdn * 1024 + 512;

    const int lane = tid & 63, wid = tid >> 6;
    const int lr = lane & 15, lg = lane >> 4;

    __syncthreads();

    for (int ch = 0; ch < 16; ++ch) {
        const int k0 = ch * 32 + half * 16;
        // (1) sfw tile via MFMA
#pragma unroll
        for (int rt = 0; rt < 2; ++rt) {
            bf16x8 af = *(const bf16x8*)&sfs_bf[((wid * 2 + rt) * 16 + lr) * 40 + lg * 8];
#pragma unroll
            for (int ct = 0; ct < 2; ++ct) {
                const int f = ch * 32 + ct * 16 + lr;
                bf16x8 bf_ = *(const bf16x8*)&wmidT[f * 16 + (lg & 1) * 8];
                f32x4 c = __builtin_amdgcn_mfma_f32_16x16x32_bf16(af, bf_, f32x4{0.f,0.f,0.f,0.f}, 0, 0, 0);
#pragma unroll
                for (int i = 0; i < 4; ++i)
                    sfw[((wid * 2 + rt) * 16 + lg * 4 + i) * 36 + ct * 16 + lr] = c[i];
            }
        }
        __syncthreads();

        // (2) build alpha*relu rows, overwriting own sfw slots
        {
            float4 r1a = *(const float4*)(q1b + k0);
            float4 r1b = *(const float4*)(q1b + k0 + 8);
            float4 r2a = *(const float4*)(q2b + k0);
            float4 r2b = *(const float4*)(q2b + k0 + 8);
            float sw[16];
            *(float4*)&sw[0]  = *(const float4*)&sfw[row * 36 + half * 16 + 0];
            *(float4*)&sw[4]  = *(const float4*)&sfw[row * 36 + half * 16 + 4];
            *(float4*)&sw[8]  = *(const float4*)&sfw[row * 36 + half * 16 + 8];
            *(float4*)&sw[12] = *(const float4*)&sfw[row * 36 + half * 16 + 12];
            float u[16], t1[8], t2[8];
            ub8(r1a, t1); ub8(r2a, t2);
#pragma unroll
            for (int k = 0; k < 8; ++k) u[k] = t1[k] + t2[k] + bes[k0 + k] + sw[k];
            ub8(r1b, t1); ub8(r2b, t2);
#pragma unroll
            for (int k = 0; k < 8; ++k) u[8 + k] = t1[k] + t2[k] + bes[k0 + 8 + k] + sw[8 + k];
            const float av = alf[row];
#pragma unroll
            for (int k = 0; k < 16; ++k) u[k] = av * fmaxf(u[k], 0.f);
            *(float4*)&sfw[row * 36 + half * 16 + 0]  = *(float4*)&u[0];
            *(float4*)&sfw[row * 36 + half * 16 + 4]  = *(float4*)&u[4];
            *(float4*)&sfw[row * 36 + half * 16 + 8]  = *(float4*)&u[8];
            *(float4*)&sfw[row * 36 + half * 16 + 12] = *(float4*)&u[12];
        }
        __syncthreads();

        // (3) segment reduce: thread = (col, 16-row stripe); one atomicAdd per run
        {
            const int c = tid & 31, g = tid >> 5;
            const int r0 = g * 16;
            float run = 0.f; int cur = pd[r0];
            for (int r = r0; r < r0 + 16; ++r) {
                run += sfw[r * 36 + c];
                const int nxt = (r < r0 + 15) ? pd[r + 1] : -1;
                if (nxt != cur) {
                    atomicAdd(&z[(size_t)cur * 512 + ch * 32 + c], run);
                    run = 0.f; cur = nxt;
                }
            }
        }
        __syncthreads();
    }
}

// ---------------- z_l aggregation: wave-per-node, bf16 out, no atomics ----------------
__global__ __launch_bounds__(256) void agg_zl_k(
    const u16* __restrict__ wv_bf, const float* __restrict__ alphal,
    const int* __restrict__ psrc, const int* __restrict__ offs,
    u16* __restrict__ zl_bf, int N, int E)
{
    const int node = blockIdx.x * 4 + (threadIdx.x >> 6);
    if (node >= N) return;
    const int lane = threadIdx.x & 63;
    const int e0 = offs[node];
    const int e1 = (node + 1 < N) ? offs[node + 1] : E;
    float acc[5] = {0.f, 0.f, 0.f, 0.f, 0.f};
    for (int e = e0; e < e1; ++e) {
        const float al = alphal[e];
        const u16* wr = wv_bf + (size_t)psrc[e] * DWP;
#pragma unroll
        for (int j = 0; j < 5; ++j) acc[j] += al * bf2f(wr[lane + 64 * j]);
    }
#pragma unroll
    for (int j = 0; j < 5; ++j) {
        const int c = lane + 64 * j;
        zl_bf[(size_t)node * DWP + c] = f2bf(c < DWR ? acc[j] : 0.f);
    }
}

// ---------------- pass 3: readout as MFMA edge-tile GEMM, sfw via MFMA ----------------
__global__ __launch_bounds__(256) void pass3_k(
    const u16* __restrict__ P, const float* __restrict__ s_f, const float* __restrict__ wmid2,
    const int* __restrict__ psrc, const int* __restrict__ pdst, const int* __restrict__ perm,
    const float* __restrict__ b_r1, const float* __restrict__ w2, const float* __restrict__ b_r2,
    float* __restrict__ out, int E)
{
    __shared__ __align__(16) u16 As[128 * 40];
    __shared__ __align__(16) u16 sfs_bf[128 * 40];
    __shared__ __align__(16) u16 wmidT[512 * 16];
    __shared__ __align__(16) u16 w2Ts[16 * 520];
    __shared__ __align__(16) float sfw[128 * 36];
    __shared__ float br1s[512];

    const int tid = threadIdx.x;
    const int e0 = xcd_swz(blockIdx.x, gridDim.x) * 128;

    for (int i = tid; i < 512 * 16; i += 256) {
        const int col = i >> 4, k = i & 15;
        wmidT[i] = f2bf(wmid2[k * 512 + col]);
    }
    for (int i = tid; i < 16 * 512; i += 256) {
        const int c = i >> 9, k = i & 511;
        w2Ts[c * 520 + k] = f2bf((c < NCLS) ? w2[k * NCLS + c] : 0.f);
    }
    for (int i = tid; i < 512; i += 256) br1s[i] = b_r1[i];

    const int row = tid >> 1, half = tid & 1;
    const int er = e0 + row;
    const int erc = (er < E) ? er : E - 1;
    {
        const int pe = perm[erc];
        const float4* sp = (const float4*)(s_f + (size_t)pe * 16 + half * 8);
        float4 a = sp[0], b = sp[1];
        union { float4 f; u16 u[8]; } S;
        S.u[0]=f2bf(a.x); S.u[1]=f2bf(a.y); S.u[2]=f2bf(a.z); S.u[3]=f2bf(a.w);
        S.u[4]=f2bf(b.x); S.u[5]=f2bf(b.y); S.u[6]=f2bf(b.z); S.u[7]=f2bf(b.w);
        *(float4*)&sfs_bf[row * 40 + half * 8] = S.f;
        S.f = float4{0.f, 0.f, 0.f, 0.f};
        *(float4*)&sfs_bf[row * 40 + 16 + half * 8] = S.f;
    }

    const int ps = psrc[erc], pd = pdst[erc];
    const u16* p1base = P + (size_t)ps * 1024;
    const u16* p2base = P + (size_t)pd * 1024 + 512;

    const int lane = tid & 63, wid = tid >> 6;
    const int lr = lane & 15, lg = lane >> 4;
    f32x4 acc0 = f32x4{0.f, 0.f, 0.f, 0.f};
    f32x4 acc1 = f32x4{0.f, 0.f, 0.f, 0.f};

    __syncthreads();

    for (int ch = 0; ch < 16; ++ch) {
        const int k0 = ch * 32 + half * 16;
#pragma unroll
        for (int rt = 0; rt < 2; ++rt) {
            bf16x8 af = *(const bf16x8*)&sfs_bf[((wid * 2 + rt) * 16 + lr) * 40 + lg * 8];
#pragma unroll
            for (int ct = 0; ct < 2; ++ct) {
                const int f = ch * 32 + ct * 16 + lr;
                bf16x8 bf_ = *(const bf16x8*)&wmidT[f * 16 + (lg & 1) * 8];
                f32x4 c = __builtin_amdgcn_mfma_f32_16x16x32_bf16(af, bf_, f32x4{0.f,0.f,0.f,0.f}, 0, 0, 0);
#pragma unroll
                for (int i = 0; i < 4; ++i)
                    sfw[((wid * 2 + rt) * 16 + lg * 4 + i) * 36 + ct * 16 + lr] = c[i];
            }
        }
        __syncthreads();

        float4 r1a = *(const float4*)(p1base + k0);
        float4 r1b = *(const float4*)(p1base + k0 + 8);
        float4 r2a = *(const float4*)(p2base + k0);
        float4 r2b = *(const float4*)(p2base + k0 + 8);
        float sw[16];
        *(float4*)&sw[0]  = *(const float4*)&sfw[row * 36 + half * 16 + 0];
        *(float4*)&sw[4]  = *(const float4*)&sfw[row * 36 + half * 16 + 4];
        *(float4*)&sw[8]  = *(const float4*)&sfw[row * 36 + half * 16 + 8];
        *(float4*)&sw[12] = *(const float4*)&sfw[row * 36 + half * 16 + 12];

        float u[16], t1[8], t2[8];
        ub8(r1a, t1); ub8(r2a, t2);
#pragma unroll
        for (int k = 0; k < 8; ++k) u[k] = t1[k] + t2[k] + br1s[k0 + k] + sw[k];
        ub8(r1b, t1); ub8(r2b, t2);
#pragma unroll
        for (int k = 0; k < 8; ++k) u[8 + k] = t1[k] + t2[k] + br1s[k0 + 8 + k] + sw[8 + k];

        union { float4 f; u16 u[8]; } Oa, Ob;
#pragma unroll
        for (int k = 0; k < 8; ++k) {
            Oa.u[k] = f2bf(fmaxf(u[k], 0.f));
            Ob.u[k] = f2bf(fmaxf(u[8 + k], 0.f));
        }
        *(float4*)&As[row * 40 + half * 16]     = Oa.f;
        *(float4*)&As[row * 40 + half * 16 + 8] = Ob.f;
        __syncthreads();

        bf16x8 af0 = *(const bf16x8*)&As[(wid * 32 +      lr) * 40 + lg * 8];
        bf16x8 af1 = *(const bf16x8*)&As[(wid * 32 + 16 + lr) * 40 + lg * 8];
        bf16x8 bfv = *(const bf16x8*)&w2Ts[lr * 520 + ch * 32 + lg * 8];
        acc0 = __builtin_amdgcn_mfma_f32_16x16x32_bf16(af0, bfv, acc0, 0, 0, 0);
        acc1 = __builtin_amdgcn_mfma_f32_16x16x32_bf16(af1, bfv, acc1, 0, 0, 0);
    }

    if (lr < NCLS) {
        const float bc = b_r2[lr];
#pragma unroll
        for (int m = 0; m < 2; ++m) {
            const f32x4 a = m ? acc1 : acc0;
            const int rbase = e0 + wid * 32 + m * 16 + lg * 4;
#pragma unroll
            for (int i = 0; i < 4; ++i) {
                const int ei = rbase + i;
                if (ei < E) out[(size_t)perm[ei] * NCLS + lr] = a[i] + bc;
            }
        }
    }
}

// ---------------- small kernels ----------------
__global__ __launch_bounds__(256) void cvt_bf(const float* __restrict__ src, u16* __restrict__ dst,
                                              int R, int Cs, int Cd)
{
    int id = blockIdx.x * 256 + threadIdx.x;
    if (id >= R * Cd) return;
    int r = id / Cd, c = id % Cd;
    float v = (c < Cs) ? src[(size_t)r * Cs + c] : 0.f;
    dst[id] = f2bf(v);
}

__global__ __launch_bounds__(256) void wtrans(const float* __restrict__ W, int Nw, int Nreal,
                                              int NrowsOut, int ldk, TSegs ts, int nseg,
                                              u16* __restrict__ WT)
{
    int id = blockIdx.x * 256 + threadIdx.x;
    if (id >= NrowsOut * ldk) return;
    int n = id / ldk, kp = id % ldk;
    float v = 0.f;
    if (n < Nreal) {
        int off = 0;
#pragma unroll
        for (int s = 0; s < 5; s++) {
            if (s < nseg) {
                int kl = kp - off;
                if (kl >= 0 && kl < ts.t[s].wpad) {
                    if (kl < ts.t[s].wreal) v = W[(size_t)(ts.t[s].src_begin + kl) * Nw + n];
                }
                off += ts.t[s].wpad;
            }
        }
    }
    WT[id] = f2bf(v);
}

__global__ __launch_bounds__(256) void hist_k(const int* __restrict__ dst, int* __restrict__ deg, int E)
{
    int id = blockIdx.x * 256 + threadIdx.x;
    if (id < E) atomicAdd(&deg[dst[id]], 1);
}

__global__ __launch_bounds__(1024) void scan_k(const int* __restrict__ deg,
                                               int* __restrict__ offs, int* __restrict__ cursor, int N)
{
    __shared__ int ps[1024];
    const int t = threadIdx.x;
    const int per = (N + 1023) >> 10;
    int s = 0;
    for (int j = 0; j < per; j++) { int idx = t * per + j; if (idx < N) s += deg[idx]; }
    ps[t] = s; __syncthreads();
    for (int o = 1; o < 1024; o <<= 1) {
        int v = (t >= o) ? ps[t - o] : 0; __syncthreads();
        ps[t] += v; __syncthreads();
    }
    int run = ps[t] - s;
    for (int j = 0; j < per; j++) {
        int idx = t * per + j;
        if (idx < N) { offs[idx] = run; cursor[idx] = run; run += deg[idx]; }
    }
}

__global__ __launch_bounds__(256) void scat_perm_k(const int* __restrict__ src, const int* __restrict__ dst,
                                                   int* __restrict__ cursor, int* __restrict__ perm,
                                                   int* __restrict__ psrc, int* __restrict__ pdst, int E)
{
    int id = blockIdx.x * 256 + threadIdx.x;
    if (id >= E) return;
    int d = dst[id];
    int pos = atomicAdd(&cursor[d], 1);
    perm[pos] = id; psrc[pos] = src[id]; pdst[pos] = d;
}

__global__ __launch_bounds__(256) void diag_fill(float* out, int n, float v)
{
    int id = blockIdx.x * 256 + threadIdx.x;
    if (id < n) out[id] = v;
}

// ---------------- host ----------------
extern "C" void kernel_launch(void* const* d_in, const int* in_sizes, int n_in,
                              void* d_out, int out_size, void* d_ws, size_t ws_size,
                              hipStream_t stream)
{
    const float* n_f  = (const float*)d_in[0];
    const float* w2v  = (const float*)d_in[1];
    const float* s_f  = (const float*)d_in[2];
    const int*   src  = (const int*)d_in[3];
    const int*   dst  = (const int*)d_in[4];
    const float* W_e  = (const float*)d_in[5];
    const float* b_e  = (const float*)d_in[6];
    const float* W_el = (const float*)d_in[7];
    const float* b_el = (const float*)d_in[8];
    const float* W_a  = (const float*)d_in[9];
    const float* b_a  = (const float*)d_in[10];
    const float* W_al = (const float*)d_in[11];
    const float* b_al = (const float*)d_in[12];
    const float* W_n  = (const float*)d_in[13];
    const float* b_n  = (const float*)d_in[14];
    const float* W_nl = (const float*)d_in[15];
    const float* b_nl = (const float*)d_in[16];
    const float* W_r1 = (const float*)d_in[17];
    const float* b_r1 = (const float*)d_in[18];
    const float* W_r2 = (const float*)d_in[19];
    const float* b_r2 = (const float*)d_in[20];

    const int N = in_sizes[0] / ND;   // 20000
    const int E = in_sizes[3];        // 320000
    float* out = (float*)d_out;

    auto g1 = [](long long n) { return dim3((unsigned)((n + 255) / 256)); };

    char* base = (char*)d_ws;
    size_t off = 0;
    auto alloc = [&](size_t bytes) -> void* {
        void* r = base + off;
        off += (bytes + 255) & ~(size_t)255;
        return r;
    };
    u16* nf_bf = (u16*)alloc((size_t)N * ND * 2);
    u16* wv_bf = (u16*)alloc((size_t)N * DWP * 2);
    u16* Q     = (u16*)alloc((size_t)N * 1024 * 2);
    u16* Lq    = (u16*)alloc((size_t)N * 1024 * 2);
    u16* Pt    = (u16*)alloc((size_t)N * 1024 * 2);
    u16* z_bf  = (u16*)alloc((size_t)N * ND * 2);
    u16* zl_bf = (u16*)alloc((size_t)N * DWP * 2);
    u16* nn_bf = (u16*)alloc((size_t)N * ND * 2);
    u16* wn_bf = (u16*)alloc((size_t)N * DWP * 2);
    u16* QT    = (u16*)alloc((size_t)1024 * 512 * 2);
    u16* LT    = (u16*)alloc((size_t)1024 * 320 * 2);
    u16* WnT   = (u16*)alloc((size_t)512 * 1024 * 2);
    u16* WnlT  = (u16*)alloc((size_t)384 * 640 * 2);
    u16* PrT   = (u16*)alloc((size_t)1024 * 832 * 2);
    float* aAs = (float*)alloc((size_t)E * 4);
    float* aLs = (float*)alloc((size_t)E * 4);
    int* deg    = (int*)alloc((size_t)N * 4);
    int* offs   = (int*)alloc((size_t)N * 4);
    int* cursor = (int*)alloc((size_t)N * 4);
    int* perm   = (int*)alloc((size_t)E * 4);
    int* psrc   = (int*)alloc((size_t)E * 4);
    int* pdst   = (int*)alloc((size_t)E * 4);
    // z fp32 accumulator aliases Lq (dead after pass1_k; same 41 MB footprint)
    float* zf = (float*)Lq;

    if (off > ws_size) {
        diag_fill<<<g1(out_size), 256, 0, stream>>>(out, out_size, 2.0e6f);
        return;
    }

    hipMemsetAsync(deg, 0, (size_t)N * 4, stream);

    // sort edges by dst
    hist_k<<<g1(E), 256, 0, stream>>>(dst, deg, E);
    scan_k<<<dim3(1), 1024, 0, stream>>>(deg, offs, cursor, N);
    scat_perm_k<<<g1(E), 256, 0, stream>>>(src, dst, cursor, perm, psrc, pdst, E);

    cvt_bf<<<g1((long long)N * ND), 256, 0, stream>>>(n_f, nf_bf, N, ND, ND);
    cvt_bf<<<g1((long long)N * DWP), 256, 0, stream>>>(w2v, wv_bf, N, DWR, DWP);

    // weight prep
    { TSegs t{}; t.t[0] = {0,512,512};
      wtrans<<<g1(512 * 512), 256, 0, stream>>>(W_e, 512, 512, 512, 512, t, 1, QT); }
    { TSegs t{}; t.t[0] = {528,512,512};
      wtrans<<<g1(512 * 512), 256, 0, stream>>>(W_e, 512, 512, 512, 512, t, 1, QT + 512 * 512); }
    { TSegs t{}; t.t[0] = {0,300,320};
      wtrans<<<g1(512 * 320), 256, 0, stream>>>(W_el, 512, 512, 512, 320, t, 1, LT); }
    { TSegs t{}; t.t[0] = {300,300,320};
      wtrans<<<g1(512 * 320), 256, 0, stream>>>(W_el, 512, 512, 512, 320, t, 1, LT + 512 * 320); }
    { TSegs t{}; t.t[0] = {0,512,512}; t.t[1] = {512,512,512};
      wtrans<<<g1(512 * 1024), 256, 0, stream>>>(W_n, 512, 512, 512, 1024, t, 2, WnT); }
    { TSegs t{}; t.t[0] = {0,300,320}; t.t[1] = {300,300,320};
      wtrans<<<g1(384 * 640), 256, 0, stream>>>(W_nl, 300, 300, 384, 640, t, 2, WnlT); }
    { TSegs t{}; t.t[0] = {0,512,512}; t.t[1] = {512,300,320};
      wtrans<<<g1(512 * 832), 256, 0, stream>>>(W_r1, 512, 512, 512, 832, t, 2, PrT); }
    { TSegs t{}; t.t[0] = {1128,512,512}; t.t[1] = {828,300,320};
      wtrans<<<g1(512 * 832), 256, 0, stream>>>(W_r1, 512, 512, 512, 832, t, 2, PrT + 512 * 832); }

    const int gmx = (N + 127) / 128;
    const dim3 gnode((N + 3) / 4);
    const dim3 gedge((E + 127) / 128);

    // node projections Q, L
    { GSegs s{}; s.s[0] = {nf_bf, nullptr, ND, 512};
      gemm_k<0><<<dim3(gmx, 8), 256, 0, stream>>>(N, 1024, s, QT, 512, nullptr, 0, Q, 1024); }
    { GSegs s{}; s.s[0] = {wv_bf, nullptr, DWP, 320};
      gemm_k<0><<<dim3(gmx, 8), 256, 0, stream>>>(N, 1024, s, LT, 320, nullptr, 0, Lq, 1024); }

    // attention logits (MFMA edge-tile) + softmax
    pass1_k<<<gedge, 256, 0, stream>>>(Q, Lq, s_f, W_e + 512 * 512,
                                       psrc, pdst, perm, W_a, W_al,
                                       b_e, b_el, b_a, b_al, aAs, aLs, E);
    softmax_k<<<gnode, 256, 0, stream>>>(aAs, aLs, offs, N, E);

    // z aggregation: edge-tile MFMA + segment reduce into fp32 (aliased on dead Lq)
    hipMemsetAsync(zf, 0, (size_t)N * 512 * 4, stream);
    passzt_k<<<gedge, 256, 0, stream>>>(Q, s_f, W_e + 512 * 512, psrc, pdst, perm,
                                        aAs, b_e, zf, E);
    agg_zl_k<<<gnode, 256, 0, stream>>>(wv_bf, aLs, psrc, offs, zl_bf, N, E);
    cvt_bf<<<g1((long long)N * ND), 256, 0, stream>>>(zf, z_bf, N, ND, ND);

    // node MLPs
    { GSegs s{}; s.s[0] = {nf_bf, nullptr, ND, 512}; s.s[1] = {z_bf, nullptr, ND, 512};
      gemm_k<1><<<dim3(gmx, 4), 256, 0, stream>>>(N, 512, s, WnT, 1024, b_n, 512, nn_bf, 512); }
    { GSegs s{}; s.s[0] = {wv_bf, nullptr, DWP, 320}; s.s[1] = {zl_bf, nullptr, DWP, 320};
      gemm_k<1><<<dim3(gmx, 3), 256, 0, stream>>>(N, 320, s, WnlT, 640, b_nl, 300, wn_bf, DWP); }

    // readout projection P
    { GSegs s{}; s.s[0] = {nn_bf, nullptr, ND, 512}; s.s[1] = {wn_bf, nullptr, DWP, 320};
      gemm_k<0><<<dim3(gmx, 8), 256, 0, stream>>>(N, 1024, s, PrT, 832, nullptr, 0, Pt, 1024); }

    // readout: MFMA edge-tile GEMM (writes original order)
    pass3_k<<<gedge, 256, 0, stream>>>(Pt, s_f, W_r1 + 812 * 512,
                                       psrc, pdst, perm, b_r1, W_r2, b_r2, out, E);

    hipError_t e = hipGetLastError();
    if (e != hipSuccess) {
        diag_fill<<<g1(out_size), 256, 0, stream>>>(out, out_size, 1.0e6f + (float)(int)e);
    }
}

// Round 14
// 884.151 us; speedup vs baseline: 1.1057x; 1.1057x over previous
//
#include <hip/hip_runtime.h>

typedef unsigned short u16;
typedef unsigned int u32;
typedef __bf16 bf16x8 __attribute__((ext_vector_type(8)));
typedef float f32x4 __attribute__((ext_vector_type(4)));

#define ND 512
#define DWR 300
#define DWP 320
#define NCLS 13

__device__ __forceinline__ float bf2f(u16 u) { return __uint_as_float(((u32)u) << 16); }
__device__ __forceinline__ u16 f2bf(float f) {
    u32 u = __float_as_uint(f);
    u32 r = (u + 0x7FFFu + ((u >> 16) & 1u)) >> 16;
    return (u16)r;
}
__device__ __forceinline__ void ub8(float4 r, float* v) {
    union { float4 f; u16 u[8]; } U; U.f = r;
#pragma unroll
    for (int k = 0; k < 8; ++k) v[k] = bf2f(U.u[k]);
}
__device__ __forceinline__ void ld8f(const u16* p, float* v) { ub8(*(const float4*)p, v); }
__device__ __forceinline__ void ld16(const float* p, float* s) {
    const float4* sp = (const float4*)p;
    float4 s0 = sp[0], s1 = sp[1], s2 = sp[2], s3 = sp[3];
    s[0]=s0.x; s[1]=s0.y; s[2]=s0.z; s[3]=s0.w; s[4]=s1.x; s[5]=s1.y; s[6]=s1.z; s[7]=s1.w;
    s[8]=s2.x; s[9]=s2.y; s[10]=s2.z; s[11]=s2.w; s[12]=s3.x; s[13]=s3.y; s[14]=s3.z; s[15]=s3.w;
}
// bijective 1-D XCD swizzle: consecutive results share an XCD
__device__ __forceinline__ int xcd_swz(int b, int gx) {
    const int q = gx >> 3, r = gx & 7;
    const int x = b & 7, o = b >> 3;
    return (x < r ? x * (q + 1) : r * (q + 1) + (x - r) * q) + o;
}

struct GSeg { const u16* base; const int* idx; int stride; int width; };
struct GSegs { GSeg s[5]; };
struct TSeg { int src_begin; int wreal; int wpad; };
struct TSegs { TSeg t[5]; };

// ---------------- node-domain GEMM: C = [relu](A @ BT^T + bias), bf16 out ----------------
template<int RELU>
__global__ __launch_bounds__(256) void gemm_k(
    int M, int Nout, GSegs segs,
    const u16* __restrict__ BT, int ldb,
    const float* __restrict__ bias, int bias_n,
    u16* __restrict__ outb, int ldo)
{
    __shared__ __align__(16) u16 As[128 * 40];
    __shared__ __align__(16) u16 Bs[128 * 40];
    const int tid = threadIdx.x;

    const int gx = gridDim.x, gy = gridDim.y;
    const int g0 = blockIdx.x + gx * blockIdx.y;
    int xt, yt;
    {
        const int fullg = gx >> 3;
        const int gsz = 8 * gy;
        if (g0 < fullg * gsz) {
            const int grp = g0 / gsz, w = g0 % gsz;
            xt = grp * 8 + (w & 7); yt = w >> 3;
        } else {
            const int remx = gx - fullg * 8;
            const int t = g0 - fullg * gsz;
            xt = fullg * 8 + t % remx; yt = t / remx;
        }
    }
    const int m0 = xt * 128, n0 = yt * 128;

    const int row = tid >> 1, half = tid & 1;
    int mrow = m0 + row; if (mrow >= M) mrow = M - 1;
    const int lane = tid & 63, wid = tid >> 6;
    const int wr = (wid >> 1) * 64, wc = (wid & 1) * 64;
    const int lr = lane & 15, lg = lane >> 4;

    f32x4 acc[4][4];
    for (int fm = 0; fm < 4; fm++)
        for (int fn = 0; fn < 4; fn++)
            acc[fm][fn] = f32x4{0.f, 0.f, 0.f, 0.f};

    const u16* brow = BT + (size_t)(n0 + row) * ldb + half * 16;

    auto do_step = [&](const u16* ga_, const u16* gb_) {
        float4 a0 = *(const float4*)ga_;
        float4 a1 = *(const float4*)(ga_ + 8);
        float4 b0 = *(const float4*)gb_;
        float4 b1 = *(const float4*)(gb_ + 8);
        __syncthreads();
        *(float4*)&As[row * 40 + half * 16]     = a0;
        *(float4*)&As[row * 40 + half * 16 + 8] = a1;
        *(float4*)&Bs[row * 40 + half * 16]     = b0;
        *(float4*)&Bs[row * 40 + half * 16 + 8] = b1;
        __syncthreads();
        bf16x8 af[4], bfv[4];
#pragma unroll
        for (int f = 0; f < 4; f++) {
            af[f]  = *(const bf16x8*)&As[(wr + f * 16 + lr) * 40 + lg * 8];
            bfv[f] = *(const bf16x8*)&Bs[(wc + f * 16 + lr) * 40 + lg * 8];
        }
#pragma unroll
        for (int fm = 0; fm < 4; fm++)
#pragma unroll
            for (int fn = 0; fn < 4; fn++)
                acc[fm][fn] = __builtin_amdgcn_mfma_f32_16x16x32_bf16(af[fm], bfv[fn], acc[fm][fn], 0, 0, 0);
    };

    int k0 = 0;
#pragma unroll
    for (int sI = 0; sI < 5; sI++) {
        const GSeg S = segs.s[sI];
        if (S.width > 0) {
            const int ridx = S.idx ? S.idx[mrow] : mrow;
            const u16* abase = S.base + (size_t)ridx * S.stride + half * 16;
            for (int kk = 0; kk < S.width; kk += 32) {
                do_step(abase + kk, brow + k0 + kk);
            }
            k0 += S.width;
        }
    }

#pragma unroll
    for (int fm = 0; fm < 4; fm++) {
#pragma unroll
        for (int i = 0; i < 4; i++) {
            const int grow = m0 + wr + fm * 16 + lg * 4 + i;
            const bool rok = grow < M;
#pragma unroll
            for (int fn = 0; fn < 4; fn++) {
                const int col = n0 + wc + fn * 16 + lr;
                float v = acc[fm][fn][i];
                v += (col < bias_n) ? bias[col] : 0.f;
                if (RELU) v = fmaxf(v, 0.f);
                if (rok && col < Nout) outb[(size_t)grow * ldo + col] = f2bf(v);
            }
        }
    }
}

// ---------------- pass 1: attention logits as MFMA edge-tile ----------------
// sfw via MFMA against GLOBAL wmT (bf16 [512][16]); sfw kept bf16 in LDS.
__global__ __launch_bounds__(256) void pass1_k(
    const u16* __restrict__ Q, const u16* __restrict__ Lq,
    const float* __restrict__ s_f, const u16* __restrict__ wmT,
    const int* __restrict__ psrc, const int* __restrict__ pdst, const int* __restrict__ perm,
    const float* __restrict__ W_a, const float* __restrict__ W_al,
    const float* __restrict__ b_e, const float* __restrict__ b_el,
    const float* __restrict__ b_a, const float* __restrict__ b_al,
    float* __restrict__ aA, float* __restrict__ aL, int E)
{
    __shared__ __align__(16) u16 sfs_bf[128 * 40];   // 10240 B
    __shared__ __align__(16) u16 As_v[128 * 40];     // 10240 B
    __shared__ __align__(16) u16 As_l[128 * 40];     // 10240 B
    __shared__ __align__(16) u16 sfwb[128 * 40];     // 10240 B (bf16 sfw tile)
    __shared__ float bes[512], bels[512];            // 4096 B
    __shared__ __align__(16) u16 was[512], wals[512]; // 2048 B  -> total 47104 B

    const int tid = threadIdx.x;
    const int e0 = xcd_swz(blockIdx.x, gridDim.x) * 128;

    for (int i = tid; i < 512; i += 256) {
        bes[i] = b_e[i]; bels[i] = b_el[i];
        was[i] = f2bf(W_a[i]); wals[i] = f2bf(W_al[i]);
    }

    const int row = tid >> 1, half = tid & 1;
    const int er = e0 + row;
    const int erc = (er < E) ? er : E - 1;
    {
        const int pe = perm[erc];
        const float4* sp = (const float4*)(s_f + (size_t)pe * 16 + half * 8);
        float4 a = sp[0], b = sp[1];
        union { float4 f; u16 u[8]; } S;
        S.u[0]=f2bf(a.x); S.u[1]=f2bf(a.y); S.u[2]=f2bf(a.z); S.u[3]=f2bf(a.w);
        S.u[4]=f2bf(b.x); S.u[5]=f2bf(b.y); S.u[6]=f2bf(b.z); S.u[7]=f2bf(b.w);
        *(float4*)&sfs_bf[row * 40 + half * 8] = S.f;
        S.f = float4{0.f, 0.f, 0.f, 0.f};
        *(float4*)&sfs_bf[row * 40 + 16 + half * 8] = S.f;
    }

    const int ps = psrc[erc], pd = pdst[erc];
    const u16* q1b = Q + (size_t)ps * 1024;
    const u16* q2b = Q + (size_t)pd * 1024 + 512;
    const u16* l1b = Lq + (size_t)ps * 1024;
    const u16* l2b = Lq + (size_t)pd * 1024 + 512;

    const int lane = tid & 63, wid = tid >> 6;
    const int lr = lane & 15, lg = lane >> 4;
    f32x4 accv[2], accl[2];
    accv[0] = accv[1] = accl[0] = accl[1] = f32x4{0.f, 0.f, 0.f, 0.f};
    union { bf16x8 v; float4 f; } BZ; BZ.f = float4{0.f, 0.f, 0.f, 0.f};

    __syncthreads();

    for (int ch = 0; ch < 16; ++ch) {
        const int k0 = ch * 32 + half * 16;
        // (1) sfw tile via MFMA; B fragments from global wmT (L1-hot 16 KB)
        bf16x8 bw[2];
#pragma unroll
        for (int ct = 0; ct < 2; ++ct)
            bw[ct] = *(const bf16x8*)&wmT[(size_t)(ch * 32 + ct * 16 + lr) * 16 + (lg & 1) * 8];
#pragma unroll
        for (int rt = 0; rt < 2; ++rt) {
            bf16x8 af = *(const bf16x8*)&sfs_bf[((wid * 2 + rt) * 16 + lr) * 40 + lg * 8];
#pragma unroll
            for (int ct = 0; ct < 2; ++ct) {
                f32x4 c = __builtin_amdgcn_mfma_f32_16x16x32_bf16(af, bw[ct], f32x4{0.f,0.f,0.f,0.f}, 0, 0, 0);
#pragma unroll
                for (int i = 0; i < 4; ++i)
                    sfwb[((wid * 2 + rt) * 16 + lg * 4 + i) * 40 + ct * 16 + lr] = f2bf(c[i]);
            }
        }
        __syncthreads();   // sfw ready; prev chunk's As reads done

        // (2) build
        float4 rq1a = *(const float4*)(q1b + k0);
        float4 rq1b = *(const float4*)(q1b + k0 + 8);
        float4 rq2a = *(const float4*)(q2b + k0);
        float4 rq2b = *(const float4*)(q2b + k0 + 8);
        float4 rl1a = *(const float4*)(l1b + k0);
        float4 rl1b = *(const float4*)(l1b + k0 + 8);
        float4 rl2a = *(const float4*)(l2b + k0);
        float4 rl2b = *(const float4*)(l2b + k0 + 8);
        float sw[16];
        ld8f(&sfwb[row * 40 + half * 16], &sw[0]);
        ld8f(&sfwb[row * 40 + half * 16 + 8], &sw[8]);

        float uv[16], ul[16], t1[8], t2[8];
        ub8(rq1a, t1); ub8(rq2a, t2);
#pragma unroll
        for (int k = 0; k < 8; ++k) uv[k] = t1[k] + t2[k] + bes[k0 + k] + sw[k];
        ub8(rq1b, t1); ub8(rq2b, t2);
#pragma unroll
        for (int k = 0; k < 8; ++k) uv[8 + k] = t1[k] + t2[k] + bes[k0 + 8 + k] + sw[8 + k];
        ub8(rl1a, t1); ub8(rl2a, t2);
#pragma unroll
        for (int k = 0; k < 8; ++k) ul[k] = t1[k] + t2[k] + bels[k0 + k];
        ub8(rl1b, t1); ub8(rl2b, t2);
#pragma unroll
        for (int k = 0; k < 8; ++k) ul[8 + k] = t1[k] + t2[k] + bels[k0 + 8 + k];

        union { float4 f; u16 u[8]; } Va, Vb, La, Lb;
#pragma unroll
        for (int k = 0; k < 8; ++k) {
            Va.u[k] = f2bf(fmaxf(uv[k], 0.f));
            Vb.u[k] = f2bf(fmaxf(uv[8 + k], 0.f));
            La.u[k] = f2bf(fmaxf(ul[k], 0.f));
            Lb.u[k] = f2bf(fmaxf(ul[8 + k], 0.f));
        }
        *(float4*)&As_v[row * 40 + half * 16]     = Va.f;
        *(float4*)&As_v[row * 40 + half * 16 + 8] = Vb.f;
        *(float4*)&As_l[row * 40 + half * 16]     = La.f;
        *(float4*)&As_l[row * 40 + half * 16 + 8] = Lb.f;
        __syncthreads();   // tiles ready

        // (3) accumulate dots via MFMA (B column 0 = weight vector)
        bf16x8 bv = BZ.v, bl = BZ.v;
        if (lr == 0) {
            bv = *(const bf16x8*)&was[ch * 32 + lg * 8];
            bl = *(const bf16x8*)&wals[ch * 32 + lg * 8];
        }
#pragma unroll
        for (int m = 0; m < 2; ++m) {
            bf16x8 afv = *(const bf16x8*)&As_v[(wid * 32 + m * 16 + lr) * 40 + lg * 8];
            bf16x8 afl = *(const bf16x8*)&As_l[(wid * 32 + m * 16 + lr) * 40 + lg * 8];
            accv[m] = __builtin_amdgcn_mfma_f32_16x16x32_bf16(afv, bv, accv[m], 0, 0, 0);
            accl[m] = __builtin_amdgcn_mfma_f32_16x16x32_bf16(afl, bl, accl[m], 0, 0, 0);
        }
    }

    if (lr == 0) {
        const float ba = b_a[0], bal = b_al[0];
#pragma unroll
        for (int m = 0; m < 2; ++m) {
#pragma unroll
            for (int i = 0; i < 4; ++i) {
                const int e = e0 + wid * 32 + m * 16 + lg * 4 + i;
                if (e < E) {
                    float x = accv[m][i] + ba;
                    aA[e] = x > 0.f ? x : 0.2f * x;
                    float y = accl[m][i] + bal;
                    aL[e] = y > 0.f ? y : 0.2f * y;
                }
            }
        }
    }
}

// ---------------- softmax: wave-per-node over sorted edges, no atomics ----------------
__global__ __launch_bounds__(256) void softmax_k(
    float* __restrict__ a, float* __restrict__ al,
    const int* __restrict__ offs, int N, int E)
{
    const int node = blockIdx.x * 4 + (threadIdx.x >> 6);
    if (node >= N) return;
    const int lane = threadIdx.x & 63;
    const int e0 = offs[node];
    const int e1 = (node + 1 < N) ? offs[node + 1] : E;
    if (e0 >= e1) return;
    float m = -3.4e38f, ml = -3.4e38f;
    for (int e = e0 + lane; e < e1; e += 64) { m = fmaxf(m, a[e]); ml = fmaxf(ml, al[e]); }
#pragma unroll
    for (int off = 32; off >= 1; off >>= 1) {
        m  = fmaxf(m,  __shfl_xor(m,  off, 64));
        ml = fmaxf(ml, __shfl_xor(ml, off, 64));
    }
    float s = 0.f, sl = 0.f;
    for (int e = e0 + lane; e < e1; e += 64) {
        float v = expf(a[e] - m);   a[e] = v;  s += v;
        float w = expf(al[e] - ml); al[e] = w; sl += w;
    }
#pragma unroll
    for (int off = 32; off >= 1; off >>= 1) {
        s  += __shfl_xor(s,  off, 64);
        sl += __shfl_xor(sl, off, 64);
    }
    const float rs = 1.f / (s + 1e-9f), rsl = 1.f / (sl + 1e-9f);
    for (int e = e0 + lane; e < e1; e += 64) { a[e] *= rs; al[e] *= rsl; }
}

// ---------------- pass z: fused z + z_l aggregation, wave-per-node (r12 proven) ----------------
__global__ __launch_bounds__(256) void passz_k(
    const u16* __restrict__ Q, const u16* __restrict__ wv_bf,
    const float* __restrict__ s_f, const float* __restrict__ wmid,
    const int* __restrict__ psrc, const int* __restrict__ perm, const int* __restrict__ offs,
    const float* __restrict__ alpha, const float* __restrict__ alphal,
    const float* __restrict__ b_e,
    u16* __restrict__ z_bf, u16* __restrict__ zl_bf, int N, int E)
{
    __shared__ __align__(16) u16 wmids[16 * 512];
    const int tid = threadIdx.x;
    for (int i = tid; i < 16 * 512; i += 256) wmids[i] = f2bf(wmid[i]);
    __syncthreads();
    const int node = blockIdx.x * 4 + (tid >> 6);
    if (node >= N) return;
    const int lane = tid & 63;
    const int col0 = lane * 8;
    const int colw = (lane < 40) ? col0 : 0;
    const int e0 = offs[node];
    const int e1 = (node + 1 < N) ? offs[node + 1] : E;

    float q2b[8], accz[8], accl[8], t[8];
    ld8f(Q + (size_t)node * 1024 + 512 + col0, q2b);
#pragma unroll
    for (int k = 0; k < 8; ++k) { q2b[k] += b_e[col0 + k]; accz[k] = 0.f; accl[k] = 0.f; }

    if (e0 < e1) {
        int ps0 = psrc[e0], pe0 = perm[e0];
        float4 rq0 = *(const float4*)(Q + (size_t)ps0 * 1024 + col0);
        float4 rw0 = *(const float4*)(wv_bf + (size_t)ps0 * DWP + colw);
        int ps1 = ps0, pe1 = pe0;
        if (e0 + 1 < e1) { ps1 = psrc[e0 + 1]; pe1 = perm[e0 + 1]; }

        for (int e = e0; e < e1; ++e) {
            float4 rq1 = rq0, rw1 = rw0;
            if (e + 1 < e1) {
                rq1 = *(const float4*)(Q + (size_t)ps1 * 1024 + col0);
                rw1 = *(const float4*)(wv_bf + (size_t)ps1 * DWP + colw);
            }
            int ps2 = ps1, pe2 = pe1;
            if (e + 2 < e1) { ps2 = psrc[e + 2]; pe2 = perm[e + 2]; }

            const float alA = alpha[e], alL = alphal[e];
            float sf[16];
            ld16(s_f + (size_t)pe0 * 16, sf);
            float v[8];
            ub8(rq0, t);
#pragma unroll
            for (int k = 0; k < 8; ++k) v[k] = t[k] + q2b[k];
#pragma unroll
            for (int j = 0; j < 16; ++j) {
                union { float4 f; u16 u[8]; } W;
                W.f = *(const float4*)&wmids[j * 512 + col0];
#pragma unroll
                for (int k = 0; k < 8; ++k) v[k] = fmaf(sf[j], bf2f(W.u[k]), v[k]);
            }
#pragma unroll
            for (int k = 0; k < 8; ++k) accz[k] = fmaf(alA, fmaxf(v[k], 0.f), accz[k]);
            ub8(rw0, t);
#pragma unroll
            for (int k = 0; k < 8; ++k) accl[k] = fmaf(alL, t[k], accl[k]);

            rq0 = rq1; rw0 = rw1; ps0 = ps1; pe0 = pe1; ps1 = ps2; pe1 = pe2;
        }
    }
    union { float4 f; u16 u[8]; } O;
#pragma unroll
    for (int k = 0; k < 8; ++k) O.u[k] = f2bf(accz[k]);
    *(float4*)(z_bf + (size_t)node * 512 + col0) = O.f;
    if (lane < 40) {
#pragma unroll
        for (int k = 0; k < 8; ++k) O.u[k] = f2bf(accl[k]);
        *(float4*)(zl_bf + (size_t)node * DWP + col0) = O.f;
    }
}

// ---------------- pass 3: readout as MFMA edge-tile GEMM (global wmT, bf16 sfw) ----------------
__global__ __launch_bounds__(256) void pass3_k(
    const u16* __restrict__ P, const float* __restrict__ s_f, const u16* __restrict__ wmT,
    const int* __restrict__ psrc, const int* __restrict__ pdst, const int* __restrict__ perm,
    const float* __restrict__ b_r1, const float* __restrict__ w2, const float* __restrict__ b_r2,
    float* __restrict__ out, int E)
{
    __shared__ __align__(16) u16 As[128 * 40];       // 10240 B
    __shared__ __align__(16) u16 sfs_bf[128 * 40];   // 10240 B
    __shared__ __align__(16) u16 sfwb[128 * 40];     // 10240 B
    __shared__ __align__(16) u16 w2Ts[16 * 520];     // 16640 B
    __shared__ float br1s[512];                      // 2048 B  -> total 49408 B

    const int tid = threadIdx.x;
    const int e0 = xcd_swz(blockIdx.x, gridDim.x) * 128;

    for (int i = tid; i < 16 * 512; i += 256) {
        const int c = i >> 9, k = i & 511;
        w2Ts[c * 520 + k] = f2bf((c < NCLS) ? w2[k * NCLS + c] : 0.f);
    }
    for (int i = tid; i < 512; i += 256) br1s[i] = b_r1[i];

    const int row = tid >> 1, half = tid & 1;
    const int er = e0 + row;
    const int erc = (er < E) ? er : E - 1;
    {
        const int pe = perm[erc];
        const float4* sp = (const float4*)(s_f + (size_t)pe * 16 + half * 8);
        float4 a = sp[0], b = sp[1];
        union { float4 f; u16 u[8]; } S;
        S.u[0]=f2bf(a.x); S.u[1]=f2bf(a.y); S.u[2]=f2bf(a.z); S.u[3]=f2bf(a.w);
        S.u[4]=f2bf(b.x); S.u[5]=f2bf(b.y); S.u[6]=f2bf(b.z); S.u[7]=f2bf(b.w);
        *(float4*)&sfs_bf[row * 40 + half * 8] = S.f;
        S.f = float4{0.f, 0.f, 0.f, 0.f};
        *(float4*)&sfs_bf[row * 40 + 16 + half * 8] = S.f;
    }

    const int ps = psrc[erc], pd = pdst[erc];
    const u16* p1base = P + (size_t)ps * 1024;
    const u16* p2base = P + (size_t)pd * 1024 + 512;

    const int lane = tid & 63, wid = tid >> 6;
    const int lr = lane & 15, lg = lane >> 4;
    f32x4 acc0 = f32x4{0.f, 0.f, 0.f, 0.f};
    f32x4 acc1 = f32x4{0.f, 0.f, 0.f, 0.f};

    __syncthreads();

    for (int ch = 0; ch < 16; ++ch) {
        const int k0 = ch * 32 + half * 16;
        bf16x8 bw[2];
#pragma unroll
        for (int ct = 0; ct < 2; ++ct)
            bw[ct] = *(const bf16x8*)&wmT[(size_t)(ch * 32 + ct * 16 + lr) * 16 + (lg & 1) * 8];
#pragma unroll
        for (int rt = 0; rt < 2; ++rt) {
            bf16x8 af = *(const bf16x8*)&sfs_bf[((wid * 2 + rt) * 16 + lr) * 40 + lg * 8];
#pragma unroll
            for (int ct = 0; ct < 2; ++ct) {
                f32x4 c = __builtin_amdgcn_mfma_f32_16x16x32_bf16(af, bw[ct], f32x4{0.f,0.f,0.f,0.f}, 0, 0, 0);
#pragma unroll
                for (int i = 0; i < 4; ++i)
                    sfwb[((wid * 2 + rt) * 16 + lg * 4 + i) * 40 + ct * 16 + lr] = f2bf(c[i]);
            }
        }
        __syncthreads();

        float4 r1a = *(const float4*)(p1base + k0);
        float4 r1b = *(const float4*)(p1base + k0 + 8);
        float4 r2a = *(const float4*)(p2base + k0);
        float4 r2b = *(const float4*)(p2base + k0 + 8);
        float sw[16];
        ld8f(&sfwb[row * 40 + half * 16], &sw[0]);
        ld8f(&sfwb[row * 40 + half * 16 + 8], &sw[8]);

        float u[16], t1[8], t2[8];
        ub8(r1a, t1); ub8(r2a, t2);
#pragma unroll
        for (int k = 0; k < 8; ++k) u[k] = t1[k] + t2[k] + br1s[k0 + k] + sw[k];
        ub8(r1b, t1); ub8(r2b, t2);
#pragma unroll
        for (int k = 0; k < 8; ++k) u[8 + k] = t1[k] + t2[k] + br1s[k0 + 8 + k] + sw[8 + k];

        union { float4 f; u16 u[8]; } Oa, Ob;
#pragma unroll
        for (int k = 0; k < 8; ++k) {
            Oa.u[k] = f2bf(fmaxf(u[k], 0.f));
            Ob.u[k] = f2bf(fmaxf(u[8 + k], 0.f));
        }
        *(float4*)&As[row * 40 + half * 16]     = Oa.f;
        *(float4*)&As[row * 40 + half * 16 + 8] = Ob.f;
        __syncthreads();

        bf16x8 af0 = *(const bf16x8*)&As[(wid * 32 +      lr) * 40 + lg * 8];
        bf16x8 af1 = *(const bf16x8*)&As[(wid * 32 + 16 + lr) * 40 + lg * 8];
        bf16x8 bfv = *(const bf16x8*)&w2Ts[lr * 520 + ch * 32 + lg * 8];
        acc0 = __builtin_amdgcn_mfma_f32_16x16x32_bf16(af0, bfv, acc0, 0, 0, 0);
        acc1 = __builtin_amdgcn_mfma_f32_16x16x32_bf16(af1, bfv, acc1, 0, 0, 0);
    }

    if (lr < NCLS) {
        const float bc = b_r2[lr];
#pragma unroll
        for (int m = 0; m < 2; ++m) {
            const f32x4 a = m ? acc1 : acc0;
            const int rbase = e0 + wid * 32 + m * 16 + lg * 4;
#pragma unroll
            for (int i = 0; i < 4; ++i) {
                const int ei = rbase + i;
                if (ei < E) out[(size_t)perm[ei] * NCLS + lr] = a[i] + bc;
            }
        }
    }
}

// ---------------- small kernels ----------------
__global__ __launch_bounds__(256) void cvt_bf(const float* __restrict__ src, u16* __restrict__ dst,
                                              int R, int Cs, int Cd)
{
    int id = blockIdx.x * 256 + threadIdx.x;
    if (id >= R * Cd) return;
    int r = id / Cd, c = id % Cd;
    float v = (c < Cs) ? src[(size_t)r * Cs + c] : 0.f;
    dst[id] = f2bf(v);
}

__global__ __launch_bounds__(256) void wtrans(const float* __restrict__ W, int Nw, int Nreal,
                                              int NrowsOut, int ldk, TSegs ts, int nseg,
                                              u16* __restrict__ WT)
{
    int id = blockIdx.x * 256 + threadIdx.x;
    if (id >= NrowsOut * ldk) return;
    int n = id / ldk, kp = id % ldk;
    float v = 0.f;
    if (n < Nreal) {
        int off = 0;
#pragma unroll
        for (int s = 0; s < 5; s++) {
            if (s < nseg) {
                int kl = kp - off;
                if (kl >= 0 && kl < ts.t[s].wpad) {
                    if (kl < ts.t[s].wreal) v = W[(size_t)(ts.t[s].src_begin + kl) * Nw + n];
                }
                off += ts.t[s].wpad;
            }
        }
    }
    WT[id] = f2bf(v);
}

__global__ __launch_bounds__(256) void hist_k(const int* __restrict__ dst, int* __restrict__ deg, int E)
{
    int id = blockIdx.x * 256 + threadIdx.x;
    if (id < E) atomicAdd(&deg[dst[id]], 1);
}

__global__ __launch_bounds__(1024) void scan_k(const int* __restrict__ deg,
                                               int* __restrict__ offs, int* __restrict__ cursor, int N)
{
    __shared__ int ps[1024];
    const int t = threadIdx.x;
    const int per = (N + 1023) >> 10;
    int s = 0;
    for (int j = 0; j < per; j++) { int idx = t * per + j; if (idx < N) s += deg[idx]; }
    ps[t] = s; __syncthreads();
    for (int o = 1; o < 1024; o <<= 1) {
        int v = (t >= o) ? ps[t - o] : 0; __syncthreads();
        ps[t] += v; __syncthreads();
    }
    int run = ps[t] - s;
    for (int j = 0; j < per; j++) {
        int idx = t * per + j;
        if (idx < N) { offs[idx] = run; cursor[idx] = run; run += deg[idx]; }
    }
}

__global__ __launch_bounds__(256) void scat_perm_k(const int* __restrict__ src, const int* __restrict__ dst,
                                                   int* __restrict__ cursor, int* __restrict__ perm,
                                                   int* __restrict__ psrc, int* __restrict__ pdst, int E)
{
    int id = blockIdx.x * 256 + threadIdx.x;
    if (id >= E) return;
    int d = dst[id];
    int pos = atomicAdd(&cursor[d], 1);
    perm[pos] = id; psrc[pos] = src[id]; pdst[pos] = d;
}

__global__ __launch_bounds__(256) void diag_fill(float* out, int n, float v)
{
    int id = blockIdx.x * 256 + threadIdx.x;
    if (id < n) out[id] = v;
}

// ---------------- host ----------------
extern "C" void kernel_launch(void* const* d_in, const int* in_sizes, int n_in,
                              void* d_out, int out_size, void* d_ws, size_t ws_size,
                              hipStream_t stream)
{
    const float* n_f  = (const float*)d_in[0];
    const float* w2v  = (const float*)d_in[1];
    const float* s_f  = (const float*)d_in[2];
    const int*   src  = (const int*)d_in[3];
    const int*   dst  = (const int*)d_in[4];
    const float* W_e  = (const float*)d_in[5];
    const float* b_e  = (const float*)d_in[6];
    const float* W_el = (const float*)d_in[7];
    const float* b_el = (const float*)d_in[8];
    const float* W_a  = (const float*)d_in[9];
    const float* b_a  = (const float*)d_in[10];
    const float* W_al = (const float*)d_in[11];
    const float* b_al = (const float*)d_in[12];
    const float* W_n  = (const float*)d_in[13];
    const float* b_n  = (const float*)d_in[14];
    const float* W_nl = (const float*)d_in[15];
    const float* b_nl = (const float*)d_in[16];
    const float* W_r1 = (const float*)d_in[17];
    const float* b_r1 = (const float*)d_in[18];
    const float* W_r2 = (const float*)d_in[19];
    const float* b_r2 = (const float*)d_in[20];

    const int N = in_sizes[0] / ND;   // 20000
    const int E = in_sizes[3];        // 320000
    float* out = (float*)d_out;

    auto g1 = [](long long n) { return dim3((unsigned)((n + 255) / 256)); };

    char* base = (char*)d_ws;
    size_t off = 0;
    auto alloc = [&](size_t bytes) -> void* {
        void* r = base + off;
        off += (bytes + 255) & ~(size_t)255;
        return r;
    };
    u16* nf_bf = (u16*)alloc((size_t)N * ND * 2);
    u16* wv_bf = (u16*)alloc((size_t)N * DWP * 2);
    u16* Q     = (u16*)alloc((size_t)N * 1024 * 2);
    u16* Lq    = (u16*)alloc((size_t)N * 1024 * 2);
    u16* Pt    = (u16*)alloc((size_t)N * 1024 * 2);
    u16* z_bf  = (u16*)alloc((size_t)N * ND * 2);
    u16* zl_bf = (u16*)alloc((size_t)N * DWP * 2);
    u16* nn_bf = (u16*)alloc((size_t)N * ND * 2);
    u16* wn_bf = (u16*)alloc((size_t)N * DWP * 2);
    u16* QT    = (u16*)alloc((size_t)1024 * 512 * 2);
    u16* LT    = (u16*)alloc((size_t)1024 * 320 * 2);
    u16* WnT   = (u16*)alloc((size_t)512 * 1024 * 2);
    u16* WnlT  = (u16*)alloc((size_t)384 * 640 * 2);
    u16* PrT   = (u16*)alloc((size_t)1024 * 832 * 2);
    u16* wmT1  = (u16*)alloc((size_t)512 * 16 * 2);
    u16* wmT2  = (u16*)alloc((size_t)512 * 16 * 2);
    float* aAs = (float*)alloc((size_t)E * 4);
    float* aLs = (float*)alloc((size_t)E * 4);
    int* deg    = (int*)alloc((size_t)N * 4);
    int* offs   = (int*)alloc((size_t)N * 4);
    int* cursor = (int*)alloc((size_t)N * 4);
    int* perm   = (int*)alloc((size_t)E * 4);
    int* psrc   = (int*)alloc((size_t)E * 4);
    int* pdst   = (int*)alloc((size_t)E * 4);

    if (off > ws_size) {
        diag_fill<<<g1(out_size), 256, 0, stream>>>(out, out_size, 2.0e6f);
        return;
    }

    hipMemsetAsync(deg, 0, (size_t)N * 4, stream);

    // sort edges by dst
    hist_k<<<g1(E), 256, 0, stream>>>(dst, deg, E);
    scan_k<<<dim3(1), 1024, 0, stream>>>(deg, offs, cursor, N);
    scat_perm_k<<<g1(E), 256, 0, stream>>>(src, dst, cursor, perm, psrc, pdst, E);

    cvt_bf<<<g1((long long)N * ND), 256, 0, stream>>>(n_f, nf_bf, N, ND, ND);
    cvt_bf<<<g1((long long)N * DWP), 256, 0, stream>>>(w2v, wv_bf, N, DWR, DWP);

    // weight prep
    { TSegs t{}; t.t[0] = {0,512,512};
      wtrans<<<g1(512 * 512), 256, 0, stream>>>(W_e, 512, 512, 512, 512, t, 1, QT); }
    { TSegs t{}; t.t[0] = {528,512,512};
      wtrans<<<g1(512 * 512), 256, 0, stream>>>(W_e, 512, 512, 512, 512, t, 1, QT + 512 * 512); }
    { TSegs t{}; t.t[0] = {0,300,320};
      wtrans<<<g1(512 * 320), 256, 0, stream>>>(W_el, 512, 512, 512, 320, t, 1, LT); }
    { TSegs t{}; t.t[0] = {300,300,320};
      wtrans<<<g1(512 * 320), 256, 0, stream>>>(W_el, 512, 512, 512, 320, t, 1, LT + 512 * 320); }
    { TSegs t{}; t.t[0] = {0,512,512}; t.t[1] = {512,512,512};
      wtrans<<<g1(512 * 1024), 256, 0, stream>>>(W_n, 512, 512, 512, 1024, t, 2, WnT); }
    { TSegs t{}; t.t[0] = {0,300,320}; t.t[1] = {300,300,320};
      wtrans<<<g1(384 * 640), 256, 0, stream>>>(W_nl, 300, 300, 384, 640, t, 2, WnlT); }
    { TSegs t{}; t.t[0] = {0,512,512}; t.t[1] = {512,300,320};
      wtrans<<<g1(512 * 832), 256, 0, stream>>>(W_r1, 512, 512, 512, 832, t, 2, PrT); }
    { TSegs t{}; t.t[0] = {1128,512,512}; t.t[1] = {828,300,320};
      wtrans<<<g1(512 * 832), 256, 0, stream>>>(W_r1, 512, 512, 512, 832, t, 2, PrT + 512 * 832); }
    // wmT tables: [col 512][k 16] bf16 (transposed wmid slices)
    { TSegs t{}; t.t[0] = {512,16,16};
      wtrans<<<g1(512 * 16), 256, 0, stream>>>(W_e, 512, 512, 512, 16, t, 1, wmT1); }
    { TSegs t{}; t.t[0] = {812,16,16};
      wtrans<<<g1(512 * 16), 256, 0, stream>>>(W_r1, 512, 512, 512, 16, t, 1, wmT2); }

    const int gmx = (N + 127) / 128;
    const dim3 gnode((N + 3) / 4);
    const dim3 gedge((E + 127) / 128);

    // node projections Q, L
    { GSegs s{}; s.s[0] = {nf_bf, nullptr, ND, 512};
      gemm_k<0><<<dim3(gmx, 8), 256, 0, stream>>>(N, 1024, s, QT, 512, nullptr, 0, Q, 1024); }
    { GSegs s{}; s.s[0] = {wv_bf, nullptr, DWP, 320};
      gemm_k<0><<<dim3(gmx, 8), 256, 0, stream>>>(N, 1024, s, LT, 320, nullptr, 0, Lq, 1024); }

    // attention logits (MFMA edge-tile) + softmax
    pass1_k<<<gedge, 256, 0, stream>>>(Q, Lq, s_f, wmT1,
                                       psrc, pdst, perm, W_a, W_al,
                                       b_e, b_el, b_a, b_al, aAs, aLs, E);
    softmax_k<<<gnode, 256, 0, stream>>>(aAs, aLs, offs, N, E);

    // fused aggregation (z + z_l), bf16 outputs directly (r12 proven path)
    passz_k<<<gnode, 256, 0, stream>>>(Q, wv_bf, s_f, W_e + 512 * 512, psrc, perm, offs,
                                       aAs, aLs, b_e, z_bf, zl_bf, N, E);

    // node MLPs
    { GSegs s{}; s.s[0] = {nf_bf, nullptr, ND, 512}; s.s[1] = {z_bf, nullptr, ND, 512};
      gemm_k<1><<<dim3(gmx, 4), 256, 0, stream>>>(N, 512, s, WnT, 1024, b_n, 512, nn_bf, 512); }
    { GSegs s{}; s.s[0] = {wv_bf, nullptr, DWP, 320}; s.s[1] = {zl_bf, nullptr, DWP, 320};
      gemm_k<1><<<dim3(gmx, 3), 256, 0, stream>>>(N, 320, s, WnlT, 640, b_nl, 300, wn_bf, DWP); }

    // readout projection P
    { GSegs s{}; s.s[0] = {nn_bf, nullptr, ND, 512}; s.s[1] = {wn_bf, nullptr, DWP, 320};
      gemm_k<0><<<dim3(gmx, 8), 256, 0, stream>>>(N, 1024, s, PrT, 832, nullptr, 0, Pt, 1024); }

    // readout: MFMA edge-tile GEMM (writes original order)
    pass3_k<<<gedge, 256, 0, stream>>>(Pt, s_f, wmT2,
                                       psrc, pdst, perm, b_r1, W_r2, b_r2, out, E);

    hipError_t e = hipGetLastError();
    if (e != hipSuccess) {
        diag_fill<<<g1(out_size), 256, 0, stream>>>(out, out_size, 1.0e6f + (float)(int)e);
    }
}

// Round 15
// 872.853 us; speedup vs baseline: 1.1200x; 1.0129x over previous
//
#include <hip/hip_runtime.h>

typedef unsigned short u16;
typedef unsigned int u32;
typedef __bf16 bf16x8 __attribute__((ext_vector_type(8)));
typedef float f32x4 __attribute__((ext_vector_type(4)));

#define ND 512
#define DWR 300
#define DWP 320
#define NCLS 13

__device__ __forceinline__ float bf2f(u16 u) { return __uint_as_float(((u32)u) << 16); }
__device__ __forceinline__ u16 f2bf(float f) {
    u32 u = __float_as_uint(f);
    u32 r = (u + 0x7FFFu + ((u >> 16) & 1u)) >> 16;
    return (u16)r;
}
__device__ __forceinline__ void ub8(float4 r, float* v) {
    union { float4 f; u16 u[8]; } U; U.f = r;
#pragma unroll
    for (int k = 0; k < 8; ++k) v[k] = bf2f(U.u[k]);
}
__device__ __forceinline__ void ld8f(const u16* p, float* v) { ub8(*(const float4*)p, v); }
__device__ __forceinline__ void ld16(const float* p, float* s) {
    const float4* sp = (const float4*)p;
    float4 s0 = sp[0], s1 = sp[1], s2 = sp[2], s3 = sp[3];
    s[0]=s0.x; s[1]=s0.y; s[2]=s0.z; s[3]=s0.w; s[4]=s1.x; s[5]=s1.y; s[6]=s1.z; s[7]=s1.w;
    s[8]=s2.x; s[9]=s2.y; s[10]=s2.z; s[11]=s2.w; s[12]=s3.x; s[13]=s3.y; s[14]=s3.z; s[15]=s3.w;
}
// bijective 1-D XCD swizzle: consecutive results share an XCD
__device__ __forceinline__ int xcd_swz(int b, int gx) {
    const int q = gx >> 3, r = gx & 7;
    const int x = b & 7, o = b >> 3;
    return (x < r ? x * (q + 1) : r * (q + 1) + (x - r) * q) + o;
}

struct GSeg { const u16* base; const int* idx; int stride; int width; };
struct GSegs { GSeg s[5]; };
struct TSeg { int src_begin; int wreal; int wpad; };
struct TSegs { TSeg t[5]; };

// ---------------- node-domain GEMM: C = [relu](A @ BT^T + bias), bf16 out ----------------
template<int RELU>
__global__ __launch_bounds__(256) void gemm_k(
    int M, int Nout, GSegs segs,
    const u16* __restrict__ BT, int ldb,
    const float* __restrict__ bias, int bias_n,
    u16* __restrict__ outb, int ldo)
{
    __shared__ __align__(16) u16 As[128 * 40];
    __shared__ __align__(16) u16 Bs[128 * 40];
    const int tid = threadIdx.x;

    const int gx = gridDim.x, gy = gridDim.y;
    const int g0 = blockIdx.x + gx * blockIdx.y;
    int xt, yt;
    {
        const int fullg = gx >> 3;
        const int gsz = 8 * gy;
        if (g0 < fullg * gsz) {
            const int grp = g0 / gsz, w = g0 % gsz;
            xt = grp * 8 + (w & 7); yt = w >> 3;
        } else {
            const int remx = gx - fullg * 8;
            const int t = g0 - fullg * gsz;
            xt = fullg * 8 + t % remx; yt = t / remx;
        }
    }
    const int m0 = xt * 128, n0 = yt * 128;

    const int row = tid >> 1, half = tid & 1;
    int mrow = m0 + row; if (mrow >= M) mrow = M - 1;
    const int lane = tid & 63, wid = tid >> 6;
    const int wr = (wid >> 1) * 64, wc = (wid & 1) * 64;
    const int lr = lane & 15, lg = lane >> 4;

    f32x4 acc[4][4];
    for (int fm = 0; fm < 4; fm++)
        for (int fn = 0; fn < 4; fn++)
            acc[fm][fn] = f32x4{0.f, 0.f, 0.f, 0.f};

    const u16* brow = BT + (size_t)(n0 + row) * ldb + half * 16;

    auto do_step = [&](const u16* ga_, const u16* gb_) {
        float4 a0 = *(const float4*)ga_;
        float4 a1 = *(const float4*)(ga_ + 8);
        float4 b0 = *(const float4*)gb_;
        float4 b1 = *(const float4*)(gb_ + 8);
        __syncthreads();
        *(float4*)&As[row * 40 + half * 16]     = a0;
        *(float4*)&As[row * 40 + half * 16 + 8] = a1;
        *(float4*)&Bs[row * 40 + half * 16]     = b0;
        *(float4*)&Bs[row * 40 + half * 16 + 8] = b1;
        __syncthreads();
        bf16x8 af[4], bfv[4];
#pragma unroll
        for (int f = 0; f < 4; f++) {
            af[f]  = *(const bf16x8*)&As[(wr + f * 16 + lr) * 40 + lg * 8];
            bfv[f] = *(const bf16x8*)&Bs[(wc + f * 16 + lr) * 40 + lg * 8];
        }
#pragma unroll
        for (int fm = 0; fm < 4; fm++)
#pragma unroll
            for (int fn = 0; fn < 4; fn++)
                acc[fm][fn] = __builtin_amdgcn_mfma_f32_16x16x32_bf16(af[fm], bfv[fn], acc[fm][fn], 0, 0, 0);
    };

    int k0 = 0;
#pragma unroll
    for (int sI = 0; sI < 5; sI++) {
        const GSeg S = segs.s[sI];
        if (S.width > 0) {
            const int ridx = S.idx ? S.idx[mrow] : mrow;
            const u16* abase = S.base + (size_t)ridx * S.stride + half * 16;
            for (int kk = 0; kk < S.width; kk += 32) {
                do_step(abase + kk, brow + k0 + kk);
            }
            k0 += S.width;
        }
    }

#pragma unroll
    for (int fm = 0; fm < 4; fm++) {
#pragma unroll
        for (int i = 0; i < 4; i++) {
            const int grow = m0 + wr + fm * 16 + lg * 4 + i;
            const bool rok = grow < M;
#pragma unroll
            for (int fn = 0; fn < 4; fn++) {
                const int col = n0 + wc + fn * 16 + lr;
                float v = acc[fm][fn][i];
                v += (col < bias_n) ? bias[col] : 0.f;
                if (RELU) v = fmaxf(v, 0.f);
                if (rok && col < Nout) outb[(size_t)grow * ldo + col] = f2bf(v);
            }
        }
    }
}

// ---------------- pass 1: attention logits as MFMA edge-tile ----------------
// sfw via MFMA against GLOBAL wmT (bf16 [512][16]); sfw kept bf16 in LDS.
__global__ __launch_bounds__(256) void pass1_k(
    const u16* __restrict__ Q, const u16* __restrict__ Lq,
    const float* __restrict__ s_f, const u16* __restrict__ wmT,
    const int* __restrict__ psrc, const int* __restrict__ pdst, const int* __restrict__ perm,
    const float* __restrict__ W_a, const float* __restrict__ W_al,
    const float* __restrict__ b_e, const float* __restrict__ b_el,
    const float* __restrict__ b_a, const float* __restrict__ b_al,
    float* __restrict__ aA, float* __restrict__ aL, int E)
{
    __shared__ __align__(16) u16 sfs_bf[128 * 40];   // 10240 B
    __shared__ __align__(16) u16 As_v[128 * 40];     // 10240 B
    __shared__ __align__(16) u16 As_l[128 * 40];     // 10240 B
    __shared__ __align__(16) u16 sfwb[128 * 40];     // 10240 B (bf16 sfw tile)
    __shared__ float bes[512], bels[512];            // 4096 B
    __shared__ __align__(16) u16 was[512], wals[512]; // 2048 B  -> total 47104 B

    const int tid = threadIdx.x;
    const int e0 = xcd_swz(blockIdx.x, gridDim.x) * 128;

    for (int i = tid; i < 512; i += 256) {
        bes[i] = b_e[i]; bels[i] = b_el[i];
        was[i] = f2bf(W_a[i]); wals[i] = f2bf(W_al[i]);
    }

    const int row = tid >> 1, half = tid & 1;
    const int er = e0 + row;
    const int erc = (er < E) ? er : E - 1;
    {
        const int pe = perm[erc];
        const float4* sp = (const float4*)(s_f + (size_t)pe * 16 + half * 8);
        float4 a = sp[0], b = sp[1];
        union { float4 f; u16 u[8]; } S;
        S.u[0]=f2bf(a.x); S.u[1]=f2bf(a.y); S.u[2]=f2bf(a.z); S.u[3]=f2bf(a.w);
        S.u[4]=f2bf(b.x); S.u[5]=f2bf(b.y); S.u[6]=f2bf(b.z); S.u[7]=f2bf(b.w);
        *(float4*)&sfs_bf[row * 40 + half * 8] = S.f;
        S.f = float4{0.f, 0.f, 0.f, 0.f};
        *(float4*)&sfs_bf[row * 40 + 16 + half * 8] = S.f;
    }

    const int ps = psrc[erc], pd = pdst[erc];
    const u16* q1b = Q + (size_t)ps * 1024;
    const u16* q2b = Q + (size_t)pd * 1024 + 512;
    const u16* l1b = Lq + (size_t)ps * 1024;
    const u16* l2b = Lq + (size_t)pd * 1024 + 512;

    const int lane = tid & 63, wid = tid >> 6;
    const int lr = lane & 15, lg = lane >> 4;
    f32x4 accv[2], accl[2];
    accv[0] = accv[1] = accl[0] = accl[1] = f32x4{0.f, 0.f, 0.f, 0.f};
    union { bf16x8 v; float4 f; } BZ; BZ.f = float4{0.f, 0.f, 0.f, 0.f};

    __syncthreads();

    for (int ch = 0; ch < 16; ++ch) {
        const int k0 = ch * 32 + half * 16;
        // (1) sfw tile via MFMA; B fragments from global wmT (L1-hot 16 KB)
        bf16x8 bw[2];
#pragma unroll
        for (int ct = 0; ct < 2; ++ct)
            bw[ct] = *(const bf16x8*)&wmT[(size_t)(ch * 32 + ct * 16 + lr) * 16 + (lg & 1) * 8];
#pragma unroll
        for (int rt = 0; rt < 2; ++rt) {
            bf16x8 af = *(const bf16x8*)&sfs_bf[((wid * 2 + rt) * 16 + lr) * 40 + lg * 8];
#pragma unroll
            for (int ct = 0; ct < 2; ++ct) {
                f32x4 c = __builtin_amdgcn_mfma_f32_16x16x32_bf16(af, bw[ct], f32x4{0.f,0.f,0.f,0.f}, 0, 0, 0);
#pragma unroll
                for (int i = 0; i < 4; ++i)
                    sfwb[((wid * 2 + rt) * 16 + lg * 4 + i) * 40 + ct * 16 + lr] = f2bf(c[i]);
            }
        }
        __syncthreads();   // sfw ready; prev chunk's As reads done

        // (2) build
        float4 rq1a = *(const float4*)(q1b + k0);
        float4 rq1b = *(const float4*)(q1b + k0 + 8);
        float4 rq2a = *(const float4*)(q2b + k0);
        float4 rq2b = *(const float4*)(q2b + k0 + 8);
        float4 rl1a = *(const float4*)(l1b + k0);
        float4 rl1b = *(const float4*)(l1b + k0 + 8);
        float4 rl2a = *(const float4*)(l2b + k0);
        float4 rl2b = *(const float4*)(l2b + k0 + 8);
        float sw[16];
        ld8f(&sfwb[row * 40 + half * 16], &sw[0]);
        ld8f(&sfwb[row * 40 + half * 16 + 8], &sw[8]);

        float uv[16], ul[16], t1[8], t2[8];
        ub8(rq1a, t1); ub8(rq2a, t2);
#pragma unroll
        for (int k = 0; k < 8; ++k) uv[k] = t1[k] + t2[k] + bes[k0 + k] + sw[k];
        ub8(rq1b, t1); ub8(rq2b, t2);
#pragma unroll
        for (int k = 0; k < 8; ++k) uv[8 + k] = t1[k] + t2[k] + bes[k0 + 8 + k] + sw[8 + k];
        ub8(rl1a, t1); ub8(rl2a, t2);
#pragma unroll
        for (int k = 0; k < 8; ++k) ul[k] = t1[k] + t2[k] + bels[k0 + k];
        ub8(rl1b, t1); ub8(rl2b, t2);
#pragma unroll
        for (int k = 0; k < 8; ++k) ul[8 + k] = t1[k] + t2[k] + bels[k0 + 8 + k];

        union { float4 f; u16 u[8]; } Va, Vb, La, Lb;
#pragma unroll
        for (int k = 0; k < 8; ++k) {
            Va.u[k] = f2bf(fmaxf(uv[k], 0.f));
            Vb.u[k] = f2bf(fmaxf(uv[8 + k], 0.f));
            La.u[k] = f2bf(fmaxf(ul[k], 0.f));
            Lb.u[k] = f2bf(fmaxf(ul[8 + k], 0.f));
        }
        *(float4*)&As_v[row * 40 + half * 16]     = Va.f;
        *(float4*)&As_v[row * 40 + half * 16 + 8] = Vb.f;
        *(float4*)&As_l[row * 40 + half * 16]     = La.f;
        *(float4*)&As_l[row * 40 + half * 16 + 8] = Lb.f;
        __syncthreads();   // tiles ready

        // (3) accumulate dots via MFMA (B column 0 = weight vector)
        bf16x8 bv = BZ.v, bl = BZ.v;
        if (lr == 0) {
            bv = *(const bf16x8*)&was[ch * 32 + lg * 8];
            bl = *(const bf16x8*)&wals[ch * 32 + lg * 8];
        }
#pragma unroll
        for (int m = 0; m < 2; ++m) {
            bf16x8 afv = *(const bf16x8*)&As_v[(wid * 32 + m * 16 + lr) * 40 + lg * 8];
            bf16x8 afl = *(const bf16x8*)&As_l[(wid * 32 + m * 16 + lr) * 40 + lg * 8];
            accv[m] = __builtin_amdgcn_mfma_f32_16x16x32_bf16(afv, bv, accv[m], 0, 0, 0);
            accl[m] = __builtin_amdgcn_mfma_f32_16x16x32_bf16(afl, bl, accl[m], 0, 0, 0);
        }
    }

    if (lr == 0) {
        const float ba = b_a[0], bal = b_al[0];
#pragma unroll
        for (int m = 0; m < 2; ++m) {
#pragma unroll
            for (int i = 0; i < 4; ++i) {
                const int e = e0 + wid * 32 + m * 16 + lg * 4 + i;
                if (e < E) {
                    float x = accv[m][i] + ba;
                    aA[e] = x > 0.f ? x : 0.2f * x;
                    float y = accl[m][i] + bal;
                    aL[e] = y > 0.f ? y : 0.2f * y;
                }
            }
        }
    }
}

// ---------------- softmax: wave-per-node over sorted edges, no atomics ----------------
__global__ __launch_bounds__(256) void softmax_k(
    float* __restrict__ a, float* __restrict__ al,
    const int* __restrict__ offs, int N, int E)
{
    const int node = blockIdx.x * 4 + (threadIdx.x >> 6);
    if (node >= N) return;
    const int lane = threadIdx.x & 63;
    const int e0 = offs[node];
    const int e1 = (node + 1 < N) ? offs[node + 1] : E;
    if (e0 >= e1) return;
    float m = -3.4e38f, ml = -3.4e38f;
    for (int e = e0 + lane; e < e1; e += 64) { m = fmaxf(m, a[e]); ml = fmaxf(ml, al[e]); }
#pragma unroll
    for (int off = 32; off >= 1; off >>= 1) {
        m  = fmaxf(m,  __shfl_xor(m,  off, 64));
        ml = fmaxf(ml, __shfl_xor(ml, off, 64));
    }
    float s = 0.f, sl = 0.f;
    for (int e = e0 + lane; e < e1; e += 64) {
        float v = expf(a[e] - m);   a[e] = v;  s += v;
        float w = expf(al[e] - ml); al[e] = w; sl += w;
    }
#pragma unroll
    for (int off = 32; off >= 1; off >>= 1) {
        s  += __shfl_xor(s,  off, 64);
        sl += __shfl_xor(sl, off, 64);
    }
    const float rs = 1.f / (s + 1e-9f), rsl = 1.f / (sl + 1e-9f);
    for (int e = e0 + lane; e < e1; e += 64) { a[e] *= rs; al[e] *= rsl; }
}

// ---------------- pass z: fused z + z_l aggregation, wave-per-node ----------------
// r15: wmid staged in LDS as f32 (no per-j bf16 unpacks in the hot loop).
__global__ __launch_bounds__(256) void passz_k(
    const u16* __restrict__ Q, const u16* __restrict__ wv_bf,
    const float* __restrict__ s_f, const float* __restrict__ wmid,
    const int* __restrict__ psrc, const int* __restrict__ perm, const int* __restrict__ offs,
    const float* __restrict__ alpha, const float* __restrict__ alphal,
    const float* __restrict__ b_e,
    u16* __restrict__ z_bf, u16* __restrict__ zl_bf, int N, int E)
{
    __shared__ __align__(16) float wmidf[16 * 512];   // 32768 B
    const int tid = threadIdx.x;
    for (int i = tid; i < 16 * 512; i += 256) wmidf[i] = wmid[i];
    __syncthreads();
    const int node = blockIdx.x * 4 + (tid >> 6);
    if (node >= N) return;
    const int lane = tid & 63;
    const int col0 = lane * 8;
    const int colw = (lane < 40) ? col0 : 0;
    const int e0 = offs[node];
    const int e1 = (node + 1 < N) ? offs[node + 1] : E;

    float q2b[8], accz[8], accl[8], t[8];
    ld8f(Q + (size_t)node * 1024 + 512 + col0, q2b);
#pragma unroll
    for (int k = 0; k < 8; ++k) { q2b[k] += b_e[col0 + k]; accz[k] = 0.f; accl[k] = 0.f; }

    if (e0 < e1) {
        int ps0 = psrc[e0], pe0 = perm[e0];
        float4 rq0 = *(const float4*)(Q + (size_t)ps0 * 1024 + col0);
        float4 rw0 = *(const float4*)(wv_bf + (size_t)ps0 * DWP + colw);
        int ps1 = ps0, pe1 = pe0;
        if (e0 + 1 < e1) { ps1 = psrc[e0 + 1]; pe1 = perm[e0 + 1]; }

        for (int e = e0; e < e1; ++e) {
            float4 rq1 = rq0, rw1 = rw0;
            if (e + 1 < e1) {
                rq1 = *(const float4*)(Q + (size_t)ps1 * 1024 + col0);
                rw1 = *(const float4*)(wv_bf + (size_t)ps1 * DWP + colw);
            }
            int ps2 = ps1, pe2 = pe1;
            if (e + 2 < e1) { ps2 = psrc[e + 2]; pe2 = perm[e + 2]; }

            const float alA = alpha[e], alL = alphal[e];
            float sf[16];
            ld16(s_f + (size_t)pe0 * 16, sf);
            float v[8];
            ub8(rq0, t);
#pragma unroll
            for (int k = 0; k < 8; ++k) v[k] = t[k] + q2b[k];
#pragma unroll
            for (int j = 0; j < 16; ++j) {
                const float sv = sf[j];
                float4 W0 = *(const float4*)&wmidf[j * 512 + col0];
                float4 W1 = *(const float4*)&wmidf[j * 512 + col0 + 4];
                v[0] = fmaf(sv, W0.x, v[0]); v[1] = fmaf(sv, W0.y, v[1]);
                v[2] = fmaf(sv, W0.z, v[2]); v[3] = fmaf(sv, W0.w, v[3]);
                v[4] = fmaf(sv, W1.x, v[4]); v[5] = fmaf(sv, W1.y, v[5]);
                v[6] = fmaf(sv, W1.z, v[6]); v[7] = fmaf(sv, W1.w, v[7]);
            }
#pragma unroll
            for (int k = 0; k < 8; ++k) accz[k] = fmaf(alA, fmaxf(v[k], 0.f), accz[k]);
            ub8(rw0, t);
#pragma unroll
            for (int k = 0; k < 8; ++k) accl[k] = fmaf(alL, t[k], accl[k]);

            rq0 = rq1; rw0 = rw1; ps0 = ps1; pe0 = pe1; ps1 = ps2; pe1 = pe2;
        }
    }
    union { float4 f; u16 u[8]; } O;
#pragma unroll
    for (int k = 0; k < 8; ++k) O.u[k] = f2bf(accz[k]);
    *(float4*)(z_bf + (size_t)node * 512 + col0) = O.f;
    if (lane < 40) {
#pragma unroll
        for (int k = 0; k < 8; ++k) O.u[k] = f2bf(accl[k]);
        *(float4*)(zl_bf + (size_t)node * DWP + col0) = O.f;
    }
}

// ---------------- pass 3: readout as MFMA edge-tile GEMM (global wmT, bf16 sfw) ----------------
__global__ __launch_bounds__(256) void pass3_k(
    const u16* __restrict__ P, const float* __restrict__ s_f, const u16* __restrict__ wmT,
    const int* __restrict__ psrc, const int* __restrict__ pdst, const int* __restrict__ perm,
    const float* __restrict__ b_r1, const float* __restrict__ w2, const float* __restrict__ b_r2,
    float* __restrict__ out, int E)
{
    __shared__ __align__(16) u16 As[128 * 40];       // 10240 B
    __shared__ __align__(16) u16 sfs_bf[128 * 40];   // 10240 B
    __shared__ __align__(16) u16 sfwb[128 * 40];     // 10240 B
    __shared__ __align__(16) u16 w2Ts[16 * 520];     // 16640 B
    __shared__ float br1s[512];                      // 2048 B  -> total 49408 B

    const int tid = threadIdx.x;
    const int e0 = xcd_swz(blockIdx.x, gridDim.x) * 128;

    for (int i = tid; i < 16 * 512; i += 256) {
        const int c = i >> 9, k = i & 511;
        w2Ts[c * 520 + k] = f2bf((c < NCLS) ? w2[k * NCLS + c] : 0.f);
    }
    for (int i = tid; i < 512; i += 256) br1s[i] = b_r1[i];

    const int row = tid >> 1, half = tid & 1;
    const int er = e0 + row;
    const int erc = (er < E) ? er : E - 1;
    {
        const int pe = perm[erc];
        const float4* sp = (const float4*)(s_f + (size_t)pe * 16 + half * 8);
        float4 a = sp[0], b = sp[1];
        union { float4 f; u16 u[8]; } S;
        S.u[0]=f2bf(a.x); S.u[1]=f2bf(a.y); S.u[2]=f2bf(a.z); S.u[3]=f2bf(a.w);
        S.u[4]=f2bf(b.x); S.u[5]=f2bf(b.y); S.u[6]=f2bf(b.z); S.u[7]=f2bf(b.w);
        *(float4*)&sfs_bf[row * 40 + half * 8] = S.f;
        S.f = float4{0.f, 0.f, 0.f, 0.f};
        *(float4*)&sfs_bf[row * 40 + 16 + half * 8] = S.f;
    }

    const int ps = psrc[erc], pd = pdst[erc];
    const u16* p1base = P + (size_t)ps * 1024;
    const u16* p2base = P + (size_t)pd * 1024 + 512;

    const int lane = tid & 63, wid = tid >> 6;
    const int lr = lane & 15, lg = lane >> 4;
    f32x4 acc0 = f32x4{0.f, 0.f, 0.f, 0.f};
    f32x4 acc1 = f32x4{0.f, 0.f, 0.f, 0.f};

    __syncthreads();

    for (int ch = 0; ch < 16; ++ch) {
        const int k0 = ch * 32 + half * 16;
        bf16x8 bw[2];
#pragma unroll
        for (int ct = 0; ct < 2; ++ct)
            bw[ct] = *(const bf16x8*)&wmT[(size_t)(ch * 32 + ct * 16 + lr) * 16 + (lg & 1) * 8];
#pragma unroll
        for (int rt = 0; rt < 2; ++rt) {
            bf16x8 af = *(const bf16x8*)&sfs_bf[((wid * 2 + rt) * 16 + lr) * 40 + lg * 8];
#pragma unroll
            for (int ct = 0; ct < 2; ++ct) {
                f32x4 c = __builtin_amdgcn_mfma_f32_16x16x32_bf16(af, bw[ct], f32x4{0.f,0.f,0.f,0.f}, 0, 0, 0);
#pragma unroll
                for (int i = 0; i < 4; ++i)
                    sfwb[((wid * 2 + rt) * 16 + lg * 4 + i) * 40 + ct * 16 + lr] = f2bf(c[i]);
            }
        }
        __syncthreads();

        float4 r1a = *(const float4*)(p1base + k0);
        float4 r1b = *(const float4*)(p1base + k0 + 8);
        float4 r2a = *(const float4*)(p2base + k0);
        float4 r2b = *(const float4*)(p2base + k0 + 8);
        float sw[16];
        ld8f(&sfwb[row * 40 + half * 16], &sw[0]);
        ld8f(&sfwb[row * 40 + half * 16 + 8], &sw[8]);

        float u[16], t1[8], t2[8];
        ub8(r1a, t1); ub8(r2a, t2);
#pragma unroll
        for (int k = 0; k < 8; ++k) u[k] = t1[k] + t2[k] + br1s[k0 + k] + sw[k];
        ub8(r1b, t1); ub8(r2b, t2);
#pragma unroll
        for (int k = 0; k < 8; ++k) u[8 + k] = t1[k] + t2[k] + br1s[k0 + 8 + k] + sw[8 + k];

        union { float4 f; u16 u[8]; } Oa, Ob;
#pragma unroll
        for (int k = 0; k < 8; ++k) {
            Oa.u[k] = f2bf(fmaxf(u[k], 0.f));
            Ob.u[k] = f2bf(fmaxf(u[8 + k], 0.f));
        }
        *(float4*)&As[row * 40 + half * 16]     = Oa.f;
        *(float4*)&As[row * 40 + half * 16 + 8] = Ob.f;
        __syncthreads();

        bf16x8 af0 = *(const bf16x8*)&As[(wid * 32 +      lr) * 40 + lg * 8];
        bf16x8 af1 = *(const bf16x8*)&As[(wid * 32 + 16 + lr) * 40 + lg * 8];
        bf16x8 bfv = *(const bf16x8*)&w2Ts[lr * 520 + ch * 32 + lg * 8];
        acc0 = __builtin_amdgcn_mfma_f32_16x16x32_bf16(af0, bfv, acc0, 0, 0, 0);
        acc1 = __builtin_amdgcn_mfma_f32_16x16x32_bf16(af1, bfv, acc1, 0, 0, 0);
    }

    if (lr < NCLS) {
        const float bc = b_r2[lr];
#pragma unroll
        for (int m = 0; m < 2; ++m) {
            const f32x4 a = m ? acc1 : acc0;
            const int rbase = e0 + wid * 32 + m * 16 + lg * 4;
#pragma unroll
            for (int i = 0; i < 4; ++i) {
                const int ei = rbase + i;
                if (ei < E) out[(size_t)perm[ei] * NCLS + lr] = a[i] + bc;
            }
        }
    }
}

// ---------------- small kernels ----------------
__global__ __launch_bounds__(256) void cvt_bf(const float* __restrict__ src, u16* __restrict__ dst,
                                              int R, int Cs, int Cd)
{
    int id = blockIdx.x * 256 + threadIdx.x;
    if (id >= R * Cd) return;
    int r = id / Cd, c = id % Cd;
    float v = (c < Cs) ? src[(size_t)r * Cs + c] : 0.f;
    dst[id] = f2bf(v);
}

__global__ __launch_bounds__(256) void wtrans(const float* __restrict__ W, int Nw, int Nreal,
                                              int NrowsOut, int ldk, TSegs ts, int nseg,
                                              u16* __restrict__ WT)
{
    int id = blockIdx.x * 256 + threadIdx.x;
    if (id >= NrowsOut * ldk) return;
    int n = id / ldk, kp = id % ldk;
    float v = 0.f;
    if (n < Nreal) {
        int off = 0;
#pragma unroll
        for (int s = 0; s < 5; s++) {
            if (s < nseg) {
                int kl = kp - off;
                if (kl >= 0 && kl < ts.t[s].wpad) {
                    if (kl < ts.t[s].wreal) v = W[(size_t)(ts.t[s].src_begin + kl) * Nw + n];
                }
                off += ts.t[s].wpad;
            }
        }
    }
    WT[id] = f2bf(v);
}

__global__ __launch_bounds__(256) void hist_k(const int* __restrict__ dst, int* __restrict__ deg, int E)
{
    int id = blockIdx.x * 256 + threadIdx.x;
    if (id < E) atomicAdd(&deg[dst[id]], 1);
}

__global__ __launch_bounds__(1024) void scan_k(const int* __restrict__ deg,
                                               int* __restrict__ offs, int* __restrict__ cursor, int N)
{
    __shared__ int ps[1024];
    const int t = threadIdx.x;
    const int per = (N + 1023) >> 10;
    int s = 0;
    for (int j = 0; j < per; j++) { int idx = t * per + j; if (idx < N) s += deg[idx]; }
    ps[t] = s; __syncthreads();
    for (int o = 1; o < 1024; o <<= 1) {
        int v = (t >= o) ? ps[t - o] : 0; __syncthreads();
        ps[t] += v; __syncthreads();
    }
    int run = ps[t] - s;
    for (int j = 0; j < per; j++) {
        int idx = t * per + j;
        if (idx < N) { offs[idx] = run; cursor[idx] = run; run += deg[idx]; }
    }
}

__global__ __launch_bounds__(256) void scat_perm_k(const int* __restrict__ src, const int* __restrict__ dst,
                                                   int* __restrict__ cursor, int* __restrict__ perm,
                                                   int* __restrict__ psrc, int* __restrict__ pdst, int E)
{
    int id = blockIdx.x * 256 + threadIdx.x;
    if (id >= E) return;
    int d = dst[id];
    int pos = atomicAdd(&cursor[d], 1);
    perm[pos] = id; psrc[pos] = src[id]; pdst[pos] = d;
}

__global__ __launch_bounds__(256) void diag_fill(float* out, int n, float v)
{
    int id = blockIdx.x * 256 + threadIdx.x;
    if (id < n) out[id] = v;
}

// ---------------- host ----------------
extern "C" void kernel_launch(void* const* d_in, const int* in_sizes, int n_in,
                              void* d_out, int out_size, void* d_ws, size_t ws_size,
                              hipStream_t stream)
{
    const float* n_f  = (const float*)d_in[0];
    const float* w2v  = (const float*)d_in[1];
    const float* s_f  = (const float*)d_in[2];
    const int*   src  = (const int*)d_in[3];
    const int*   dst  = (const int*)d_in[4];
    const float* W_e  = (const float*)d_in[5];
    const float* b_e  = (const float*)d_in[6];
    const float* W_el = (const float*)d_in[7];
    const float* b_el = (const float*)d_in[8];
    const float* W_a  = (const float*)d_in[9];
    const float* b_a  = (const float*)d_in[10];
    const float* W_al = (const float*)d_in[11];
    const float* b_al = (const float*)d_in[12];
    const float* W_n  = (const float*)d_in[13];
    const float* b_n  = (const float*)d_in[14];
    const float* W_nl = (const float*)d_in[15];
    const float* b_nl = (const float*)d_in[16];
    const float* W_r1 = (const float*)d_in[17];
    const float* b_r1 = (const float*)d_in[18];
    const float* W_r2 = (const float*)d_in[19];
    const float* b_r2 = (const float*)d_in[20];

    const int N = in_sizes[0] / ND;   // 20000
    const int E = in_sizes[3];        // 320000
    float* out = (float*)d_out;

    auto g1 = [](long long n) { return dim3((unsigned)((n + 255) / 256)); };

    char* base = (char*)d_ws;
    size_t off = 0;
    auto alloc = [&](size_t bytes) -> void* {
        void* r = base + off;
        off += (bytes + 255) & ~(size_t)255;
        return r;
    };
    u16* nf_bf = (u16*)alloc((size_t)N * ND * 2);
    u16* wv_bf = (u16*)alloc((size_t)N * DWP * 2);
    u16* Q     = (u16*)alloc((size_t)N * 1024 * 2);
    u16* Lq    = (u16*)alloc((size_t)N * 1024 * 2);
    u16* Pt    = (u16*)alloc((size_t)N * 1024 * 2);
    u16* z_bf  = (u16*)alloc((size_t)N * ND * 2);
    u16* zl_bf = (u16*)alloc((size_t)N * DWP * 2);
    u16* nn_bf = (u16*)alloc((size_t)N * ND * 2);
    u16* wn_bf = (u16*)alloc((size_t)N * DWP * 2);
    u16* QT    = (u16*)alloc((size_t)1024 * 512 * 2);
    u16* LT    = (u16*)alloc((size_t)1024 * 320 * 2);
    u16* WnT   = (u16*)alloc((size_t)512 * 1024 * 2);
    u16* WnlT  = (u16*)alloc((size_t)384 * 640 * 2);
    u16* PrT   = (u16*)alloc((size_t)1024 * 832 * 2);
    u16* wmT1  = (u16*)alloc((size_t)512 * 16 * 2);
    u16* wmT2  = (u16*)alloc((size_t)512 * 16 * 2);
    float* aAs = (float*)alloc((size_t)E * 4);
    float* aLs = (float*)alloc((size_t)E * 4);
    int* deg    = (int*)alloc((size_t)N * 4);
    int* offs   = (int*)alloc((size_t)N * 4);
    int* cursor = (int*)alloc((size_t)N * 4);
    int* perm   = (int*)alloc((size_t)E * 4);
    int* psrc   = (int*)alloc((size_t)E * 4);
    int* pdst   = (int*)alloc((size_t)E * 4);

    if (off > ws_size) {
        diag_fill<<<g1(out_size), 256, 0, stream>>>(out, out_size, 2.0e6f);
        return;
    }

    hipMemsetAsync(deg, 0, (size_t)N * 4, stream);

    // sort edges by dst
    hist_k<<<g1(E), 256, 0, stream>>>(dst, deg, E);
    scan_k<<<dim3(1), 1024, 0, stream>>>(deg, offs, cursor, N);
    scat_perm_k<<<g1(E), 256, 0, stream>>>(src, dst, cursor, perm, psrc, pdst, E);

    cvt_bf<<<g1((long long)N * ND), 256, 0, stream>>>(n_f, nf_bf, N, ND, ND);
    cvt_bf<<<g1((long long)N * DWP), 256, 0, stream>>>(w2v, wv_bf, N, DWR, DWP);

    // weight prep
    { TSegs t{}; t.t[0] = {0,512,512};
      wtrans<<<g1(512 * 512), 256, 0, stream>>>(W_e, 512, 512, 512, 512, t, 1, QT); }
    { TSegs t{}; t.t[0] = {528,512,512};
      wtrans<<<g1(512 * 512), 256, 0, stream>>>(W_e, 512, 512, 512, 512, t, 1, QT + 512 * 512); }
    { TSegs t{}; t.t[0] = {0,300,320};
      wtrans<<<g1(512 * 320), 256, 0, stream>>>(W_el, 512, 512, 512, 320, t, 1, LT); }
    { TSegs t{}; t.t[0] = {300,300,320};
      wtrans<<<g1(512 * 320), 256, 0, stream>>>(W_el, 512, 512, 512, 320, t, 1, LT + 512 * 320); }
    { TSegs t{}; t.t[0] = {0,512,512}; t.t[1] = {512,512,512};
      wtrans<<<g1(512 * 1024), 256, 0, stream>>>(W_n, 512, 512, 512, 1024, t, 2, WnT); }
    { TSegs t{}; t.t[0] = {0,300,320}; t.t[1] = {300,300,320};
      wtrans<<<g1(384 * 640), 256, 0, stream>>>(W_nl, 300, 300, 384, 640, t, 2, WnlT); }
    { TSegs t{}; t.t[0] = {0,512,512}; t.t[1] = {512,300,320};
      wtrans<<<g1(512 * 832), 256, 0, stream>>>(W_r1, 512, 512, 512, 832, t, 2, PrT); }
    { TSegs t{}; t.t[0] = {1128,512,512}; t.t[1] = {828,300,320};
      wtrans<<<g1(512 * 832), 256, 0, stream>>>(W_r1, 512, 512, 512, 832, t, 2, PrT + 512 * 832); }
    // wmT tables: [col 512][k 16] bf16 (transposed wmid slices)
    { TSegs t{}; t.t[0] = {512,16,16};
      wtrans<<<g1(512 * 16), 256, 0, stream>>>(W_e, 512, 512, 512, 16, t, 1, wmT1); }
    { TSegs t{}; t.t[0] = {812,16,16};
      wtrans<<<g1(512 * 16), 256, 0, stream>>>(W_r1, 512, 512, 512, 16, t, 1, wmT2); }

    const int gmx = (N + 127) / 128;
    const dim3 gnode((N + 3) / 4);
    const dim3 gedge((E + 127) / 128);

    // node projections Q, L
    { GSegs s{}; s.s[0] = {nf_bf, nullptr, ND, 512};
      gemm_k<0><<<dim3(gmx, 8), 256, 0, stream>>>(N, 1024, s, QT, 512, nullptr, 0, Q, 1024); }
    { GSegs s{}; s.s[0] = {wv_bf, nullptr, DWP, 320};
      gemm_k<0><<<dim3(gmx, 8), 256, 0, stream>>>(N, 1024, s, LT, 320, nullptr, 0, Lq, 1024); }

    // attention logits (MFMA edge-tile) + softmax
    pass1_k<<<gedge, 256, 0, stream>>>(Q, Lq, s_f, wmT1,
                                       psrc, pdst, perm, W_a, W_al,
                                       b_e, b_el, b_a, b_al, aAs, aLs, E);
    softmax_k<<<gnode, 256, 0, stream>>>(aAs, aLs, offs, N, E);

    // fused aggregation (z + z_l), bf16 outputs directly
    passz_k<<<gnode, 256, 0, stream>>>(Q, wv_bf, s_f, W_e + 512 * 512, psrc, perm, offs,
                                       aAs, aLs, b_e, z_bf, zl_bf, N, E);

    // node MLPs
    { GSegs s{}; s.s[0] = {nf_bf, nullptr, ND, 512}; s.s[1] = {z_bf, nullptr, ND, 512};
      gemm_k<1><<<dim3(gmx, 4), 256, 0, stream>>>(N, 512, s, WnT, 1024, b_n, 512, nn_bf, 512); }
    { GSegs s{}; s.s[0] = {wv_bf, nullptr, DWP, 320}; s.s[1] = {zl_bf, nullptr, DWP, 320};
      gemm_k<1><<<dim3(gmx, 3), 256, 0, stream>>>(N, 320, s, WnlT, 640, b_nl, 300, wn_bf, DWP); }

    // readout projection P
    { GSegs s{}; s.s[0] = {nn_bf, nullptr, ND, 512}; s.s[1] = {wn_bf, nullptr, DWP, 320};
      gemm_k<0><<<dim3(gmx, 8), 256, 0, stream>>>(N, 1024, s, PrT, 832, nullptr, 0, Pt, 1024); }

    // readout: MFMA edge-tile GEMM (writes original order)
    pass3_k<<<gedge, 256, 0, stream>>>(Pt, s_f, wmT2,
                                       psrc, pdst, perm, b_r1, W_r2, b_r2, out, E);

    hipError_t e = hipGetLastError();
    if (e != hipSuccess) {
        diag_fill<<<g1(out_size), 256, 0, stream>>>(out, out_size, 1.0e6f + (float)(int)e);
    }
}

// Round 16
// 862.753 us; speedup vs baseline: 1.1331x; 1.0117x over previous
//
#include <hip/hip_runtime.h>

typedef unsigned short u16;
typedef unsigned int u32;
typedef __bf16 bf16x8 __attribute__((ext_vector_type(8)));
typedef float f32x4 __attribute__((ext_vector_type(4)));

#define ND 512
#define DWR 300
#define DWP 320
#define NCLS 13

__device__ __forceinline__ float bf2f(u16 u) { return __uint_as_float(((u32)u) << 16); }
__device__ __forceinline__ u16 f2bf(float f) {
    u32 u = __float_as_uint(f);
    u32 r = (u + 0x7FFFu + ((u >> 16) & 1u)) >> 16;
    return (u16)r;
}
__device__ __forceinline__ void ub8(float4 r, float* v) {
    union { float4 f; u16 u[8]; } U; U.f = r;
#pragma unroll
    for (int k = 0; k < 8; ++k) v[k] = bf2f(U.u[k]);
}
__device__ __forceinline__ void ld8f(const u16* p, float* v) { ub8(*(const float4*)p, v); }
__device__ __forceinline__ void ld16(const float* p, float* s) {
    const float4* sp = (const float4*)p;
    float4 s0 = sp[0], s1 = sp[1], s2 = sp[2], s3 = sp[3];
    s[0]=s0.x; s[1]=s0.y; s[2]=s0.z; s[3]=s0.w; s[4]=s1.x; s[5]=s1.y; s[6]=s1.z; s[7]=s1.w;
    s[8]=s2.x; s[9]=s2.y; s[10]=s2.z; s[11]=s2.w; s[12]=s3.x; s[13]=s3.y; s[14]=s3.z; s[15]=s3.w;
}
// bijective 1-D XCD swizzle: consecutive results share an XCD
__device__ __forceinline__ int xcd_swz(int b, int gx) {
    const int q = gx >> 3, r = gx & 7;
    const int x = b & 7, o = b >> 3;
    return (x < r ? x * (q + 1) : r * (q + 1) + (x - r) * q) + o;
}

struct GSeg { const u16* base; const int* idx; int stride; int width; };
struct GSegs { GSeg s[5]; };
struct TSeg { int src_begin; int wreal; int wpad; };
struct TSegs { TSeg t[5]; };

// ---------------- node-domain GEMM: C = [relu](A @ BT^T + bias), bf16 out ----------------
template<int RELU>
__global__ __launch_bounds__(256) void gemm_k(
    int M, int Nout, GSegs segs,
    const u16* __restrict__ BT, int ldb,
    const float* __restrict__ bias, int bias_n,
    u16* __restrict__ outb, int ldo)
{
    __shared__ __align__(16) u16 As[128 * 40];
    __shared__ __align__(16) u16 Bs[128 * 40];
    const int tid = threadIdx.x;

    const int gx = gridDim.x, gy = gridDim.y;
    const int g0 = blockIdx.x + gx * blockIdx.y;
    int xt, yt;
    {
        const int fullg = gx >> 3;
        const int gsz = 8 * gy;
        if (g0 < fullg * gsz) {
            const int grp = g0 / gsz, w = g0 % gsz;
            xt = grp * 8 + (w & 7); yt = w >> 3;
        } else {
            const int remx = gx - fullg * 8;
            const int t = g0 - fullg * gsz;
            xt = fullg * 8 + t % remx; yt = t / remx;
        }
    }
    const int m0 = xt * 128, n0 = yt * 128;

    const int row = tid >> 1, half = tid & 1;
    int mrow = m0 + row; if (mrow >= M) mrow = M - 1;
    const int lane = tid & 63, wid = tid >> 6;
    const int wr = (wid >> 1) * 64, wc = (wid & 1) * 64;
    const int lr = lane & 15, lg = lane >> 4;

    f32x4 acc[4][4];
    for (int fm = 0; fm < 4; fm++)
        for (int fn = 0; fn < 4; fn++)
            acc[fm][fn] = f32x4{0.f, 0.f, 0.f, 0.f};

    const u16* brow = BT + (size_t)(n0 + row) * ldb + half * 16;

    auto do_step = [&](const u16* ga_, const u16* gb_) {
        float4 a0 = *(const float4*)ga_;
        float4 a1 = *(const float4*)(ga_ + 8);
        float4 b0 = *(const float4*)gb_;
        float4 b1 = *(const float4*)(gb_ + 8);
        __syncthreads();
        *(float4*)&As[row * 40 + half * 16]     = a0;
        *(float4*)&As[row * 40 + half * 16 + 8] = a1;
        *(float4*)&Bs[row * 40 + half * 16]     = b0;
        *(float4*)&Bs[row * 40 + half * 16 + 8] = b1;
        __syncthreads();
        bf16x8 af[4], bfv[4];
#pragma unroll
        for (int f = 0; f < 4; f++) {
            af[f]  = *(const bf16x8*)&As[(wr + f * 16 + lr) * 40 + lg * 8];
            bfv[f] = *(const bf16x8*)&Bs[(wc + f * 16 + lr) * 40 + lg * 8];
        }
#pragma unroll
        for (int fm = 0; fm < 4; fm++)
#pragma unroll
            for (int fn = 0; fn < 4; fn++)
                acc[fm][fn] = __builtin_amdgcn_mfma_f32_16x16x32_bf16(af[fm], bfv[fn], acc[fm][fn], 0, 0, 0);
    };

    int k0 = 0;
#pragma unroll
    for (int sI = 0; sI < 5; sI++) {
        const GSeg S = segs.s[sI];
        if (S.width > 0) {
            const int ridx = S.idx ? S.idx[mrow] : mrow;
            const u16* abase = S.base + (size_t)ridx * S.stride + half * 16;
            for (int kk = 0; kk < S.width; kk += 32) {
                do_step(abase + kk, brow + k0 + kk);
            }
            k0 += S.width;
        }
    }

#pragma unroll
    for (int fm = 0; fm < 4; fm++) {
#pragma unroll
        for (int i = 0; i < 4; i++) {
            const int grow = m0 + wr + fm * 16 + lg * 4 + i;
            const bool rok = grow < M;
#pragma unroll
            for (int fn = 0; fn < 4; fn++) {
                const int col = n0 + wc + fn * 16 + lr;
                float v = acc[fm][fn][i];
                v += (col < bias_n) ? bias[col] : 0.f;
                if (RELU) v = fmaxf(v, 0.f);
                if (rok && col < Nout) outb[(size_t)grow * ldo + col] = f2bf(v);
            }
        }
    }
}

// ---------------- pass 1: attention logits as MFMA edge-tile ----------------
// sfw via MFMA against GLOBAL wmT (bf16 [512][16]); sfw kept bf16 in LDS.
__global__ __launch_bounds__(256) void pass1_k(
    const u16* __restrict__ Q, const u16* __restrict__ Lq,
    const float* __restrict__ s_f, const u16* __restrict__ wmT,
    const int* __restrict__ psrc, const int* __restrict__ pdst, const int* __restrict__ perm,
    const float* __restrict__ W_a, const float* __restrict__ W_al,
    const float* __restrict__ b_e, const float* __restrict__ b_el,
    const float* __restrict__ b_a, const float* __restrict__ b_al,
    float* __restrict__ aA, float* __restrict__ aL, int E)
{
    __shared__ __align__(16) u16 sfs_bf[128 * 40];   // 10240 B
    __shared__ __align__(16) u16 As_v[128 * 40];     // 10240 B
    __shared__ __align__(16) u16 As_l[128 * 40];     // 10240 B
    __shared__ __align__(16) u16 sfwb[128 * 40];     // 10240 B (bf16 sfw tile)
    __shared__ float bes[512], bels[512];            // 4096 B
    __shared__ __align__(16) u16 was[512], wals[512]; // 2048 B  -> total 47104 B

    const int tid = threadIdx.x;
    const int e0 = xcd_swz(blockIdx.x, gridDim.x) * 128;

    for (int i = tid; i < 512; i += 256) {
        bes[i] = b_e[i]; bels[i] = b_el[i];
        was[i] = f2bf(W_a[i]); wals[i] = f2bf(W_al[i]);
    }

    const int row = tid >> 1, half = tid & 1;
    const int er = e0 + row;
    const int erc = (er < E) ? er : E - 1;
    {
        const int pe = perm[erc];
        const float4* sp = (const float4*)(s_f + (size_t)pe * 16 + half * 8);
        float4 a = sp[0], b = sp[1];
        union { float4 f; u16 u[8]; } S;
        S.u[0]=f2bf(a.x); S.u[1]=f2bf(a.y); S.u[2]=f2bf(a.z); S.u[3]=f2bf(a.w);
        S.u[4]=f2bf(b.x); S.u[5]=f2bf(b.y); S.u[6]=f2bf(b.z); S.u[7]=f2bf(b.w);
        *(float4*)&sfs_bf[row * 40 + half * 8] = S.f;
        S.f = float4{0.f, 0.f, 0.f, 0.f};
        *(float4*)&sfs_bf[row * 40 + 16 + half * 8] = S.f;
    }

    const int ps = psrc[erc], pd = pdst[erc];
    const u16* q1b = Q + (size_t)ps * 1024;
    const u16* q2b = Q + (size_t)pd * 1024 + 512;
    const u16* l1b = Lq + (size_t)ps * 1024;
    const u16* l2b = Lq + (size_t)pd * 1024 + 512;

    const int lane = tid & 63, wid = tid >> 6;
    const int lr = lane & 15, lg = lane >> 4;
    f32x4 accv[2], accl[2];
    accv[0] = accv[1] = accl[0] = accl[1] = f32x4{0.f, 0.f, 0.f, 0.f};
    union { bf16x8 v; float4 f; } BZ; BZ.f = float4{0.f, 0.f, 0.f, 0.f};

    __syncthreads();

    for (int ch = 0; ch < 16; ++ch) {
        const int k0 = ch * 32 + half * 16;
        // (1) sfw tile via MFMA; B fragments from global wmT (L1-hot 16 KB)
        bf16x8 bw[2];
#pragma unroll
        for (int ct = 0; ct < 2; ++ct)
            bw[ct] = *(const bf16x8*)&wmT[(size_t)(ch * 32 + ct * 16 + lr) * 16 + (lg & 1) * 8];
#pragma unroll
        for (int rt = 0; rt < 2; ++rt) {
            bf16x8 af = *(const bf16x8*)&sfs_bf[((wid * 2 + rt) * 16 + lr) * 40 + lg * 8];
#pragma unroll
            for (int ct = 0; ct < 2; ++ct) {
                f32x4 c = __builtin_amdgcn_mfma_f32_16x16x32_bf16(af, bw[ct], f32x4{0.f,0.f,0.f,0.f}, 0, 0, 0);
#pragma unroll
                for (int i = 0; i < 4; ++i)
                    sfwb[((wid * 2 + rt) * 16 + lg * 4 + i) * 40 + ct * 16 + lr] = f2bf(c[i]);
            }
        }
        __syncthreads();   // sfw ready; prev chunk's As reads done

        // (2) build
        float4 rq1a = *(const float4*)(q1b + k0);
        float4 rq1b = *(const float4*)(q1b + k0 + 8);
        float4 rq2a = *(const float4*)(q2b + k0);
        float4 rq2b = *(const float4*)(q2b + k0 + 8);
        float4 rl1a = *(const float4*)(l1b + k0);
        float4 rl1b = *(const float4*)(l1b + k0 + 8);
        float4 rl2a = *(const float4*)(l2b + k0);
        float4 rl2b = *(const float4*)(l2b + k0 + 8);
        float sw[16];
        ld8f(&sfwb[row * 40 + half * 16], &sw[0]);
        ld8f(&sfwb[row * 40 + half * 16 + 8], &sw[8]);

        float uv[16], ul[16], t1[8], t2[8];
        ub8(rq1a, t1); ub8(rq2a, t2);
#pragma unroll
        for (int k = 0; k < 8; ++k) uv[k] = t1[k] + t2[k] + bes[k0 + k] + sw[k];
        ub8(rq1b, t1); ub8(rq2b, t2);
#pragma unroll
        for (int k = 0; k < 8; ++k) uv[8 + k] = t1[k] + t2[k] + bes[k0 + 8 + k] + sw[8 + k];
        ub8(rl1a, t1); ub8(rl2a, t2);
#pragma unroll
        for (int k = 0; k < 8; ++k) ul[k] = t1[k] + t2[k] + bels[k0 + k];
        ub8(rl1b, t1); ub8(rl2b, t2);
#pragma unroll
        for (int k = 0; k < 8; ++k) ul[8 + k] = t1[k] + t2[k] + bels[k0 + 8 + k];

        union { float4 f; u16 u[8]; } Va, Vb, La, Lb;
#pragma unroll
        for (int k = 0; k < 8; ++k) {
            Va.u[k] = f2bf(fmaxf(uv[k], 0.f));
            Vb.u[k] = f2bf(fmaxf(uv[8 + k], 0.f));
            La.u[k] = f2bf(fmaxf(ul[k], 0.f));
            Lb.u[k] = f2bf(fmaxf(ul[8 + k], 0.f));
        }
        *(float4*)&As_v[row * 40 + half * 16]     = Va.f;
        *(float4*)&As_v[row * 40 + half * 16 + 8] = Vb.f;
        *(float4*)&As_l[row * 40 + half * 16]     = La.f;
        *(float4*)&As_l[row * 40 + half * 16 + 8] = Lb.f;
        __syncthreads();   // tiles ready

        // (3) accumulate dots via MFMA (B column 0 = weight vector)
        bf16x8 bv = BZ.v, bl = BZ.v;
        if (lr == 0) {
            bv = *(const bf16x8*)&was[ch * 32 + lg * 8];
            bl = *(const bf16x8*)&wals[ch * 32 + lg * 8];
        }
#pragma unroll
        for (int m = 0; m < 2; ++m) {
            bf16x8 afv = *(const bf16x8*)&As_v[(wid * 32 + m * 16 + lr) * 40 + lg * 8];
            bf16x8 afl = *(const bf16x8*)&As_l[(wid * 32 + m * 16 + lr) * 40 + lg * 8];
            accv[m] = __builtin_amdgcn_mfma_f32_16x16x32_bf16(afv, bv, accv[m], 0, 0, 0);
            accl[m] = __builtin_amdgcn_mfma_f32_16x16x32_bf16(afl, bl, accl[m], 0, 0, 0);
        }
    }

    if (lr == 0) {
        const float ba = b_a[0], bal = b_al[0];
#pragma unroll
        for (int m = 0; m < 2; ++m) {
#pragma unroll
            for (int i = 0; i < 4; ++i) {
                const int e = e0 + wid * 32 + m * 16 + lg * 4 + i;
                if (e < E) {
                    float x = accv[m][i] + ba;
                    aA[e] = x > 0.f ? x : 0.2f * x;
                    float y = accl[m][i] + bal;
                    aL[e] = y > 0.f ? y : 0.2f * y;
                }
            }
        }
    }
}

// ---------------- softmax: wave-per-node over sorted edges, no atomics ----------------
__global__ __launch_bounds__(256) void softmax_k(
    float* __restrict__ a, float* __restrict__ al,
    const int* __restrict__ offs, int N, int E)
{
    const int node = blockIdx.x * 4 + (threadIdx.x >> 6);
    if (node >= N) return;
    const int lane = threadIdx.x & 63;
    const int e0 = offs[node];
    const int e1 = (node + 1 < N) ? offs[node + 1] : E;
    if (e0 >= e1) return;
    float m = -3.4e38f, ml = -3.4e38f;
    for (int e = e0 + lane; e < e1; e += 64) { m = fmaxf(m, a[e]); ml = fmaxf(ml, al[e]); }
#pragma unroll
    for (int off = 32; off >= 1; off >>= 1) {
        m  = fmaxf(m,  __shfl_xor(m,  off, 64));
        ml = fmaxf(ml, __shfl_xor(ml, off, 64));
    }
    float s = 0.f, sl = 0.f;
    for (int e = e0 + lane; e < e1; e += 64) {
        float v = expf(a[e] - m);   a[e] = v;  s += v;
        float w = expf(al[e] - ml); al[e] = w; sl += w;
    }
#pragma unroll
    for (int off = 32; off >= 1; off >>= 1) {
        s  += __shfl_xor(s,  off, 64);
        sl += __shfl_xor(sl, off, 64);
    }
    const float rs = 1.f / (s + 1e-9f), rsl = 1.f / (sl + 1e-9f);
    for (int e = e0 + lane; e < e1; e += 64) { a[e] *= rs; al[e] *= rsl; }
}

// ---------------- pass z: fused z + z_l aggregation, wave-per-node ----------------
// r16: 2-edge pairing shares each wmid LDS read across two edges (halves LDS BW,
// which r15 counters showed to be the binding constraint).
__global__ __launch_bounds__(256) void passz_k(
    const u16* __restrict__ Q, const u16* __restrict__ wv_bf,
    const float* __restrict__ s_f, const float* __restrict__ wmid,
    const int* __restrict__ psrc, const int* __restrict__ perm, const int* __restrict__ offs,
    const float* __restrict__ alpha, const float* __restrict__ alphal,
    const float* __restrict__ b_e,
    u16* __restrict__ z_bf, u16* __restrict__ zl_bf, int N, int E)
{
    __shared__ __align__(16) float wmidf[16 * 512];   // 32768 B
    const int tid = threadIdx.x;
    for (int i = tid; i < 16 * 512; i += 256) wmidf[i] = wmid[i];
    __syncthreads();
    const int node = blockIdx.x * 4 + (tid >> 6);
    if (node >= N) return;
    const int lane = tid & 63;
    const int col0 = lane * 8;
    const int colw = (lane < 40) ? col0 : 0;
    const int e0 = offs[node];
    const int e1 = (node + 1 < N) ? offs[node + 1] : E;

    float q2b[8], accz[8], accl[8], t[8];
    ld8f(Q + (size_t)node * 1024 + 512 + col0, q2b);
#pragma unroll
    for (int k = 0; k < 8; ++k) { q2b[k] += b_e[col0 + k]; accz[k] = 0.f; accl[k] = 0.f; }

    int e = e0;
    // pair loop: one wmid read feeds both edges
    for (; e + 1 < e1; e += 2) {
        const int psA = psrc[e],     peA = perm[e];
        const int psB = psrc[e + 1], peB = perm[e + 1];
        float4 rqA = *(const float4*)(Q + (size_t)psA * 1024 + col0);
        float4 rqB = *(const float4*)(Q + (size_t)psB * 1024 + col0);
        float4 rwA = *(const float4*)(wv_bf + (size_t)psA * DWP + colw);
        float4 rwB = *(const float4*)(wv_bf + (size_t)psB * DWP + colw);
        float sfA[16], sfB[16];
        ld16(s_f + (size_t)peA * 16, sfA);
        ld16(s_f + (size_t)peB * 16, sfB);
        const float aA_ = alpha[e], aB_ = alpha[e + 1];
        const float lA_ = alphal[e], lB_ = alphal[e + 1];

        float vA[8], vB[8];
        ub8(rqA, t);
#pragma unroll
        for (int k = 0; k < 8; ++k) vA[k] = t[k] + q2b[k];
        ub8(rqB, t);
#pragma unroll
        for (int k = 0; k < 8; ++k) vB[k] = t[k] + q2b[k];
#pragma unroll
        for (int j = 0; j < 16; ++j) {
            const float sA = sfA[j], sB = sfB[j];
            float4 W0 = *(const float4*)&wmidf[j * 512 + col0];
            float4 W1 = *(const float4*)&wmidf[j * 512 + col0 + 4];
            vA[0] = fmaf(sA, W0.x, vA[0]); vB[0] = fmaf(sB, W0.x, vB[0]);
            vA[1] = fmaf(sA, W0.y, vA[1]); vB[1] = fmaf(sB, W0.y, vB[1]);
            vA[2] = fmaf(sA, W0.z, vA[2]); vB[2] = fmaf(sB, W0.z, vB[2]);
            vA[3] = fmaf(sA, W0.w, vA[3]); vB[3] = fmaf(sB, W0.w, vB[3]);
            vA[4] = fmaf(sA, W1.x, vA[4]); vB[4] = fmaf(sB, W1.x, vB[4]);
            vA[5] = fmaf(sA, W1.y, vA[5]); vB[5] = fmaf(sB, W1.y, vB[5]);
            vA[6] = fmaf(sA, W1.z, vA[6]); vB[6] = fmaf(sB, W1.z, vB[6]);
            vA[7] = fmaf(sA, W1.w, vA[7]); vB[7] = fmaf(sB, W1.w, vB[7]);
        }
#pragma unroll
        for (int k = 0; k < 8; ++k)
            accz[k] += aA_ * fmaxf(vA[k], 0.f) + aB_ * fmaxf(vB[k], 0.f);
        ub8(rwA, t);
#pragma unroll
        for (int k = 0; k < 8; ++k) accl[k] = fmaf(lA_, t[k], accl[k]);
        ub8(rwB, t);
#pragma unroll
        for (int k = 0; k < 8; ++k) accl[k] = fmaf(lB_, t[k], accl[k]);
    }
    // tail edge
    for (; e < e1; ++e) {
        const int ps = psrc[e], pe = perm[e];
        float4 rq = *(const float4*)(Q + (size_t)ps * 1024 + col0);
        float4 rw = *(const float4*)(wv_bf + (size_t)ps * DWP + colw);
        float sf[16];
        ld16(s_f + (size_t)pe * 16, sf);
        const float alA = alpha[e], alL = alphal[e];
        float v[8];
        ub8(rq, t);
#pragma unroll
        for (int k = 0; k < 8; ++k) v[k] = t[k] + q2b[k];
#pragma unroll
        for (int j = 0; j < 16; ++j) {
            const float sv = sf[j];
            float4 W0 = *(const float4*)&wmidf[j * 512 + col0];
            float4 W1 = *(const float4*)&wmidf[j * 512 + col0 + 4];
            v[0] = fmaf(sv, W0.x, v[0]); v[1] = fmaf(sv, W0.y, v[1]);
            v[2] = fmaf(sv, W0.z, v[2]); v[3] = fmaf(sv, W0.w, v[3]);
            v[4] = fmaf(sv, W1.x, v[4]); v[5] = fmaf(sv, W1.y, v[5]);
            v[6] = fmaf(sv, W1.z, v[6]); v[7] = fmaf(sv, W1.w, v[7]);
        }
#pragma unroll
        for (int k = 0; k < 8; ++k) accz[k] = fmaf(alA, fmaxf(v[k], 0.f), accz[k]);
        ub8(rw, t);
#pragma unroll
        for (int k = 0; k < 8; ++k) accl[k] = fmaf(alL, t[k], accl[k]);
    }

    union { float4 f; u16 u[8]; } O;
#pragma unroll
    for (int k = 0; k < 8; ++k) O.u[k] = f2bf(accz[k]);
    *(float4*)(z_bf + (size_t)node * 512 + col0) = O.f;
    if (lane < 40) {
#pragma unroll
        for (int k = 0; k < 8; ++k) O.u[k] = f2bf(accl[k]);
        *(float4*)(zl_bf + (size_t)node * DWP + col0) = O.f;
    }
}

// ---------------- pass 3: readout as MFMA edge-tile GEMM (global wmT, bf16 sfw) ----------------
__global__ __launch_bounds__(256) void pass3_k(
    const u16* __restrict__ P, const float* __restrict__ s_f, const u16* __restrict__ wmT,
    const int* __restrict__ psrc, const int* __restrict__ pdst, const int* __restrict__ perm,
    const float* __restrict__ b_r1, const float* __restrict__ w2, const float* __restrict__ b_r2,
    float* __restrict__ out, int E)
{
    __shared__ __align__(16) u16 As[128 * 40];       // 10240 B
    __shared__ __align__(16) u16 sfs_bf[128 * 40];   // 10240 B
    __shared__ __align__(16) u16 sfwb[128 * 40];     // 10240 B
    __shared__ __align__(16) u16 w2Ts[16 * 520];     // 16640 B
    __shared__ float br1s[512];                      // 2048 B  -> total 49408 B

    const int tid = threadIdx.x;
    const int e0 = xcd_swz(blockIdx.x, gridDim.x) * 128;

    for (int i = tid; i < 16 * 512; i += 256) {
        const int c = i >> 9, k = i & 511;
        w2Ts[c * 520 + k] = f2bf((c < NCLS) ? w2[k * NCLS + c] : 0.f);
    }
    for (int i = tid; i < 512; i += 256) br1s[i] = b_r1[i];

    const int row = tid >> 1, half = tid & 1;
    const int er = e0 + row;
    const int erc = (er < E) ? er : E - 1;
    {
        const int pe = perm[erc];
        const float4* sp = (const float4*)(s_f + (size_t)pe * 16 + half * 8);
        float4 a = sp[0], b = sp[1];
        union { float4 f; u16 u[8]; } S;
        S.u[0]=f2bf(a.x); S.u[1]=f2bf(a.y); S.u[2]=f2bf(a.z); S.u[3]=f2bf(a.w);
        S.u[4]=f2bf(b.x); S.u[5]=f2bf(b.y); S.u[6]=f2bf(b.z); S.u[7]=f2bf(b.w);
        *(float4*)&sfs_bf[row * 40 + half * 8] = S.f;
        S.f = float4{0.f, 0.f, 0.f, 0.f};
        *(float4*)&sfs_bf[row * 40 + 16 + half * 8] = S.f;
    }

    const int ps = psrc[erc], pd = pdst[erc];
    const u16* p1base = P + (size_t)ps * 1024;
    const u16* p2base = P + (size_t)pd * 1024 + 512;

    const int lane = tid & 63, wid = tid >> 6;
    const int lr = lane & 15, lg = lane >> 4;
    f32x4 acc0 = f32x4{0.f, 0.f, 0.f, 0.f};
    f32x4 acc1 = f32x4{0.f, 0.f, 0.f, 0.f};

    __syncthreads();

    for (int ch = 0; ch < 16; ++ch) {
        const int k0 = ch * 32 + half * 16;
        bf16x8 bw[2];
#pragma unroll
        for (int ct = 0; ct < 2; ++ct)
            bw[ct] = *(const bf16x8*)&wmT[(size_t)(ch * 32 + ct * 16 + lr) * 16 + (lg & 1) * 8];
#pragma unroll
        for (int rt = 0; rt < 2; ++rt) {
            bf16x8 af = *(const bf16x8*)&sfs_bf[((wid * 2 + rt) * 16 + lr) * 40 + lg * 8];
#pragma unroll
            for (int ct = 0; ct < 2; ++ct) {
                f32x4 c = __builtin_amdgcn_mfma_f32_16x16x32_bf16(af, bw[ct], f32x4{0.f,0.f,0.f,0.f}, 0, 0, 0);
#pragma unroll
                for (int i = 0; i < 4; ++i)
                    sfwb[((wid * 2 + rt) * 16 + lg * 4 + i) * 40 + ct * 16 + lr] = f2bf(c[i]);
            }
        }
        __syncthreads();

        float4 r1a = *(const float4*)(p1base + k0);
        float4 r1b = *(const float4*)(p1base + k0 + 8);
        float4 r2a = *(const float4*)(p2base + k0);
        float4 r2b = *(const float4*)(p2base + k0 + 8);
        float sw[16];
        ld8f(&sfwb[row * 40 + half * 16], &sw[0]);
        ld8f(&sfwb[row * 40 + half * 16 + 8], &sw[8]);

        float u[16], t1[8], t2[8];
        ub8(r1a, t1); ub8(r2a, t2);
#pragma unroll
        for (int k = 0; k < 8; ++k) u[k] = t1[k] + t2[k] + br1s[k0 + k] + sw[k];
        ub8(r1b, t1); ub8(r2b, t2);
#pragma unroll
        for (int k = 0; k < 8; ++k) u[8 + k] = t1[k] + t2[k] + br1s[k0 + 8 + k] + sw[8 + k];

        union { float4 f; u16 u[8]; } Oa, Ob;
#pragma unroll
        for (int k = 0; k < 8; ++k) {
            Oa.u[k] = f2bf(fmaxf(u[k], 0.f));
            Ob.u[k] = f2bf(fmaxf(u[8 + k], 0.f));
        }
        *(float4*)&As[row * 40 + half * 16]     = Oa.f;
        *(float4*)&As[row * 40 + half * 16 + 8] = Ob.f;
        __syncthreads();

        bf16x8 af0 = *(const bf16x8*)&As[(wid * 32 +      lr) * 40 + lg * 8];
        bf16x8 af1 = *(const bf16x8*)&As[(wid * 32 + 16 + lr) * 40 + lg * 8];
        bf16x8 bfv = *(const bf16x8*)&w2Ts[lr * 520 + ch * 32 + lg * 8];
        acc0 = __builtin_amdgcn_mfma_f32_16x16x32_bf16(af0, bfv, acc0, 0, 0, 0);
        acc1 = __builtin_amdgcn_mfma_f32_16x16x32_bf16(af1, bfv, acc1, 0, 0, 0);
    }

    if (lr < NCLS) {
        const float bc = b_r2[lr];
#pragma unroll
        for (int m = 0; m < 2; ++m) {
            const f32x4 a = m ? acc1 : acc0;
            const int rbase = e0 + wid * 32 + m * 16 + lg * 4;
#pragma unroll
            for (int i = 0; i < 4; ++i) {
                const int ei = rbase + i;
                if (ei < E) out[(size_t)perm[ei] * NCLS + lr] = a[i] + bc;
            }
        }
    }
}

// ---------------- small kernels ----------------
__global__ __launch_bounds__(256) void cvt_bf(const float* __restrict__ src, u16* __restrict__ dst,
                                              int R, int Cs, int Cd)
{
    int id = blockIdx.x * 256 + threadIdx.x;
    if (id >= R * Cd) return;
    int r = id / Cd, c = id % Cd;
    float v = (c < Cs) ? src[(size_t)r * Cs + c] : 0.f;
    dst[id] = f2bf(v);
}

__global__ __launch_bounds__(256) void wtrans(const float* __restrict__ W, int Nw, int Nreal,
                                              int NrowsOut, int ldk, TSegs ts, int nseg,
                                              u16* __restrict__ WT)
{
    int id = blockIdx.x * 256 + threadIdx.x;
    if (id >= NrowsOut * ldk) return;
    int n = id / ldk, kp = id % ldk;
    float v = 0.f;
    if (n < Nreal) {
        int off = 0;
#pragma unroll
        for (int s = 0; s < 5; s++) {
            if (s < nseg) {
                int kl = kp - off;
                if (kl >= 0 && kl < ts.t[s].wpad) {
                    if (kl < ts.t[s].wreal) v = W[(size_t)(ts.t[s].src_begin + kl) * Nw + n];
                }
                off += ts.t[s].wpad;
            }
        }
    }
    WT[id] = f2bf(v);
}

__global__ __launch_bounds__(256) void hist_k(const int* __restrict__ dst, int* __restrict__ deg, int E)
{
    int id = blockIdx.x * 256 + threadIdx.x;
    if (id < E) atomicAdd(&deg[dst[id]], 1);
}

__global__ __launch_bounds__(1024) void scan_k(const int* __restrict__ deg,
                                               int* __restrict__ offs, int* __restrict__ cursor, int N)
{
    __shared__ int ps[1024];
    const int t = threadIdx.x;
    const int per = (N + 1023) >> 10;
    int s = 0;
    for (int j = 0; j < per; j++) { int idx = t * per + j; if (idx < N) s += deg[idx]; }
    ps[t] = s; __syncthreads();
    for (int o = 1; o < 1024; o <<= 1) {
        int v = (t >= o) ? ps[t - o] : 0; __syncthreads();
        ps[t] += v; __syncthreads();
    }
    int run = ps[t] - s;
    for (int j = 0; j < per; j++) {
        int idx = t * per + j;
        if (idx < N) { offs[idx] = run; cursor[idx] = run; run += deg[idx]; }
    }
}

__global__ __launch_bounds__(256) void scat_perm_k(const int* __restrict__ src, const int* __restrict__ dst,
                                                   int* __restrict__ cursor, int* __restrict__ perm,
                                                   int* __restrict__ psrc, int* __restrict__ pdst, int E)
{
    int id = blockIdx.x * 256 + threadIdx.x;
    if (id >= E) return;
    int d = dst[id];
    int pos = atomicAdd(&cursor[d], 1);
    perm[pos] = id; psrc[pos] = src[id]; pdst[pos] = d;
}

__global__ __launch_bounds__(256) void diag_fill(float* out, int n, float v)
{
    int id = blockIdx.x * 256 + threadIdx.x;
    if (id < n) out[id] = v;
}

// ---------------- host ----------------
extern "C" void kernel_launch(void* const* d_in, const int* in_sizes, int n_in,
                              void* d_out, int out_size, void* d_ws, size_t ws_size,
                              hipStream_t stream)
{
    const float* n_f  = (const float*)d_in[0];
    const float* w2v  = (const float*)d_in[1];
    const float* s_f  = (const float*)d_in[2];
    const int*   src  = (const int*)d_in[3];
    const int*   dst  = (const int*)d_in[4];
    const float* W_e  = (const float*)d_in[5];
    const float* b_e  = (const float*)d_in[6];
    const float* W_el = (const float*)d_in[7];
    const float* b_el = (const float*)d_in[8];
    const float* W_a  = (const float*)d_in[9];
    const float* b_a  = (const float*)d_in[10];
    const float* W_al = (const float*)d_in[11];
    const float* b_al = (const float*)d_in[12];
    const float* W_n  = (const float*)d_in[13];
    const float* b_n  = (const float*)d_in[14];
    const float* W_nl = (const float*)d_in[15];
    const float* b_nl = (const float*)d_in[16];
    const float* W_r1 = (const float*)d_in[17];
    const float* b_r1 = (const float*)d_in[18];
    const float* W_r2 = (const float*)d_in[19];
    const float* b_r2 = (const float*)d_in[20];

    const int N = in_sizes[0] / ND;   // 20000
    const int E = in_sizes[3];        // 320000
    float* out = (float*)d_out;

    auto g1 = [](long long n) { return dim3((unsigned)((n + 255) / 256)); };

    char* base = (char*)d_ws;
    size_t off = 0;
    auto alloc = [&](size_t bytes) -> void* {
        void* r = base + off;
        off += (bytes + 255) & ~(size_t)255;
        return r;
    };
    u16* nf_bf = (u16*)alloc((size_t)N * ND * 2);
    u16* wv_bf = (u16*)alloc((size_t)N * DWP * 2);
    u16* Q     = (u16*)alloc((size_t)N * 1024 * 2);
    u16* Lq    = (u16*)alloc((size_t)N * 1024 * 2);
    u16* Pt    = (u16*)alloc((size_t)N * 1024 * 2);
    u16* z_bf  = (u16*)alloc((size_t)N * ND * 2);
    u16* zl_bf = (u16*)alloc((size_t)N * DWP * 2);
    u16* nn_bf = (u16*)alloc((size_t)N * ND * 2);
    u16* wn_bf = (u16*)alloc((size_t)N * DWP * 2);
    u16* QT    = (u16*)alloc((size_t)1024 * 512 * 2);
    u16* LT    = (u16*)alloc((size_t)1024 * 320 * 2);
    u16* WnT   = (u16*)alloc((size_t)512 * 1024 * 2);
    u16* WnlT  = (u16*)alloc((size_t)384 * 640 * 2);
    u16* PrT   = (u16*)alloc((size_t)1024 * 832 * 2);
    u16* wmT1  = (u16*)alloc((size_t)512 * 16 * 2);
    u16* wmT2  = (u16*)alloc((size_t)512 * 16 * 2);
    float* aAs = (float*)alloc((size_t)E * 4);
    float* aLs = (float*)alloc((size_t)E * 4);
    int* deg    = (int*)alloc((size_t)N * 4);
    int* offs   = (int*)alloc((size_t)N * 4);
    int* cursor = (int*)alloc((size_t)N * 4);
    int* perm   = (int*)alloc((size_t)E * 4);
    int* psrc   = (int*)alloc((size_t)E * 4);
    int* pdst   = (int*)alloc((size_t)E * 4);

    if (off > ws_size) {
        diag_fill<<<g1(out_size), 256, 0, stream>>>(out, out_size, 2.0e6f);
        return;
    }

    hipMemsetAsync(deg, 0, (size_t)N * 4, stream);

    // sort edges by dst
    hist_k<<<g1(E), 256, 0, stream>>>(dst, deg, E);
    scan_k<<<dim3(1), 1024, 0, stream>>>(deg, offs, cursor, N);
    scat_perm_k<<<g1(E), 256, 0, stream>>>(src, dst, cursor, perm, psrc, pdst, E);

    cvt_bf<<<g1((long long)N * ND), 256, 0, stream>>>(n_f, nf_bf, N, ND, ND);
    cvt_bf<<<g1((long long)N * DWP), 256, 0, stream>>>(w2v, wv_bf, N, DWR, DWP);

    // weight prep
    { TSegs t{}; t.t[0] = {0,512,512};
      wtrans<<<g1(512 * 512), 256, 0, stream>>>(W_e, 512, 512, 512, 512, t, 1, QT); }
    { TSegs t{}; t.t[0] = {528,512,512};
      wtrans<<<g1(512 * 512), 256, 0, stream>>>(W_e, 512, 512, 512, 512, t, 1, QT + 512 * 512); }
    { TSegs t{}; t.t[0] = {0,300,320};
      wtrans<<<g1(512 * 320), 256, 0, stream>>>(W_el, 512, 512, 512, 320, t, 1, LT); }
    { TSegs t{}; t.t[0] = {300,300,320};
      wtrans<<<g1(512 * 320), 256, 0, stream>>>(W_el, 512, 512, 512, 320, t, 1, LT + 512 * 320); }
    { TSegs t{}; t.t[0] = {0,512,512}; t.t[1] = {512,512,512};
      wtrans<<<g1(512 * 1024), 256, 0, stream>>>(W_n, 512, 512, 512, 1024, t, 2, WnT); }
    { TSegs t{}; t.t[0] = {0,300,320}; t.t[1] = {300,300,320};
      wtrans<<<g1(384 * 640), 256, 0, stream>>>(W_nl, 300, 300, 384, 640, t, 2, WnlT); }
    { TSegs t{}; t.t[0] = {0,512,512}; t.t[1] = {512,300,320};
      wtrans<<<g1(512 * 832), 256, 0, stream>>>(W_r1, 512, 512, 512, 832, t, 2, PrT); }
    { TSegs t{}; t.t[0] = {1128,512,512}; t.t[1] = {828,300,320};
      wtrans<<<g1(512 * 832), 256, 0, stream>>>(W_r1, 512, 512, 512, 832, t, 2, PrT + 512 * 832); }
    // wmT tables: [col 512][k 16] bf16 (transposed wmid slices)
    { TSegs t{}; t.t[0] = {512,16,16};
      wtrans<<<g1(512 * 16), 256, 0, stream>>>(W_e, 512, 512, 512, 16, t, 1, wmT1); }
    { TSegs t{}; t.t[0] = {812,16,16};
      wtrans<<<g1(512 * 16), 256, 0, stream>>>(W_r1, 512, 512, 512, 16, t, 1, wmT2); }

    const int gmx = (N + 127) / 128;
    const dim3 gnode((N + 3) / 4);
    const dim3 gedge((E + 127) / 128);

    // node projections Q, L
    { GSegs s{}; s.s[0] = {nf_bf, nullptr, ND, 512};
      gemm_k<0><<<dim3(gmx, 8), 256, 0, stream>>>(N, 1024, s, QT, 512, nullptr, 0, Q, 1024); }
    { GSegs s{}; s.s[0] = {wv_bf, nullptr, DWP, 320};
      gemm_k<0><<<dim3(gmx, 8), 256, 0, stream>>>(N, 1024, s, LT, 320, nullptr, 0, Lq, 1024); }

    // attention logits (MFMA edge-tile) + softmax
    pass1_k<<<gedge, 256, 0, stream>>>(Q, Lq, s_f, wmT1,
                                       psrc, pdst, perm, W_a, W_al,
                                       b_e, b_el, b_a, b_al, aAs, aLs, E);
    softmax_k<<<gnode, 256, 0, stream>>>(aAs, aLs, offs, N, E);

    // fused aggregation (z + z_l), bf16 outputs directly
    passz_k<<<gnode, 256, 0, stream>>>(Q, wv_bf, s_f, W_e + 512 * 512, psrc, perm, offs,
                                       aAs, aLs, b_e, z_bf, zl_bf, N, E);

    // node MLPs
    { GSegs s{}; s.s[0] = {nf_bf, nullptr, ND, 512}; s.s[1] = {z_bf, nullptr, ND, 512};
      gemm_k<1><<<dim3(gmx, 4), 256, 0, stream>>>(N, 512, s, WnT, 1024, b_n, 512, nn_bf, 512); }
    { GSegs s{}; s.s[0] = {wv_bf, nullptr, DWP, 320}; s.s[1] = {zl_bf, nullptr, DWP, 320};
      gemm_k<1><<<dim3(gmx, 3), 256, 0, stream>>>(N, 320, s, WnlT, 640, b_nl, 300, wn_bf, DWP); }

    // readout projection P
    { GSegs s{}; s.s[0] = {nn_bf, nullptr, ND, 512}; s.s[1] = {wn_bf, nullptr, DWP, 320};
      gemm_k<0><<<dim3(gmx, 8), 256, 0, stream>>>(N, 1024, s, PrT, 832, nullptr, 0, Pt, 1024); }

    // readout: MFMA edge-tile GEMM (writes original order)
    pass3_k<<<gedge, 256, 0, stream>>>(Pt, s_f, wmT2,
                                       psrc, pdst, perm, b_r1, W_r2, b_r2, out, E);

    hipError_t e = hipGetLastError();
    if (e != hipSuccess) {
        diag_fill<<<g1(out_size), 256, 0, stream>>>(out, out_size, 1.0e6f + (float)(int)e);
    }
}